// Round 1
// baseline (981.077 us; speedup 1.0000x reference)
//
#include <hip/hip_runtime.h>
#include <math.h>

// Problem constants (compile-time)
constexpr int C    = 96;
constexpr int L2   = 49;    // tokens per window (7x7)
constexpr int NH   = 3;
constexpr int Dh   = 32;
constexpr int WS   = 7;
constexpr int HH   = 56;
constexpr int HW   = 3136;  // 56*56
constexpr int NWIN = 64;    // 8x8 windows
constexpr int NT   = 512;   // threads in attn kernel

// ---------------------------------------------------------------------------
// Kernel 1: per-window fused  gather(roll+partition) -> LN1 -> QKV -> attn
//           (bias + shift mask + softmax) -> AV -> proj -> scatter(+residual)
// One block per (batch, window). Writes x2 = x + attn_out into `out`.
// ---------------------------------------------------------------------------
__global__ __launch_bounds__(NT) void attn_kernel(
    const float* __restrict__ x,
    const float* __restrict__ qkv_w,   // [96][288]
    const float* __restrict__ qkv_b,   // [288]
    const float* __restrict__ attn_bias, // [3][49][49]
    const float* __restrict__ proj_w,  // [96][96]
    const float* __restrict__ proj_b,  // [96]
    const float* __restrict__ ln1_g,
    const float* __restrict__ ln1_b,
    float* __restrict__ out)
{
    __shared__ float xw[L2 * C];        // 18816 B: gathered window, then LN'd
    __shared__ float qkv[L2 * 3 * C];   // 56448 B: q|k|v per token; reused for proj out
    __shared__ float osm[L2 * C];       // 18816 B: attention output (all heads)
    __shared__ float s[L2 * L2];        // 9604 B: scores for one head
    __shared__ float mu[L2], rs[L2];
    __shared__ float g1[C], b1[C];

    const int blk = blockIdx.x;
    const int b   = blk >> 6;          // / 64 windows
    const int w   = blk & 63;
    const int wh  = w >> 3, ww = w & 7;
    const int tid = threadIdx.x;

    if (tid < C) { g1[tid] = ln1_g[tid]; b1[tid] = ln1_b[tid]; }

    // ---- gather window from rolled image -------------------------------
    for (int idx = tid; idx < L2 * C; idx += NT) {
        int t = idx / C, c = idx - t * C;
        int i = t / WS, j = t - i * WS;
        int row = wh * WS + i + 3; if (row >= HH) row -= HH;
        int col = ww * WS + j + 3; if (col >= HH) col -= HH;
        xw[idx] = x[((size_t)b * HW + row * HH + col) * C + c];
    }
    __syncthreads();

    // ---- LN1 stats (one thread per token) -------------------------------
    if (tid < L2) {
        float sum = 0.f, sq = 0.f;
        for (int c = 0; c < C; ++c) { float v = xw[tid * C + c]; sum += v; sq += v * v; }
        float m = sum * (1.0f / C);
        float var = sq * (1.0f / C) - m * m;
        mu[tid] = m; rs[tid] = rsqrtf(var + 1e-5f);
    }
    __syncthreads();
    for (int idx = tid; idx < L2 * C; idx += NT) {
        int t = idx / C, c = idx - t * C;
        xw[idx] = (xw[idx] - mu[t]) * rs[t] * g1[c] + b1[c];
    }
    __syncthreads();

    // ---- QKV GEMM: [49,96] @ [96,288]; 7 tok x 4 out register tile -------
    if (tid < 504) {
        int tt = tid / 72, og = tid - tt * 72;     // tt in [0,7), og in [0,72)
        int o0 = og * 4, t0 = tt * 7;
        float acc[7][4];
        #pragma unroll
        for (int a = 0; a < 7; ++a)
            for (int d = 0; d < 4; ++d) acc[a][d] = qkv_b[o0 + d];
        for (int c = 0; c < C; ++c) {
            float4 wv = *(const float4*)&qkv_w[c * 288 + o0];
            #pragma unroll
            for (int a = 0; a < 7; ++a) {
                float xv = xw[(t0 + a) * C + c];
                acc[a][0] += xv * wv.x; acc[a][1] += xv * wv.y;
                acc[a][2] += xv * wv.z; acc[a][3] += xv * wv.w;
            }
        }
        #pragma unroll
        for (int a = 0; a < 7; ++a)
            for (int d = 0; d < 4; ++d) qkv[(t0 + a) * 288 + o0 + d] = acc[a][d];
    }
    __syncthreads();

    // ---- attention per head ----------------------------------------------
    const float scale = 0.17677669529663687f; // 32^-0.5
    for (int h = 0; h < NH; ++h) {
        // scores: q.k*scale + bias + shift-window mask
        for (int idx = tid; idx < L2 * L2; idx += NT) {
            int q = idx / L2, k = idx - q * L2;
            const float* qp = &qkv[q * 288 + h * Dh];
            const float* kp = &qkv[k * 288 + C + h * Dh];
            float acc = 0.f;
            #pragma unroll
            for (int d = 0; d < Dh; ++d) acc += qp[d] * kp[d];
            acc = acc * scale + attn_bias[(h * L2 + q) * L2 + k];
            // shift mask via region labels in rolled coords
            int qi = q / WS, qj = q - qi * WS;
            int ki = k / WS, kj = k - ki * WS;
            int qrow = wh * WS + qi, qcol = ww * WS + qj;
            int krow = wh * WS + ki, kcol = ww * WS + kj;
            int lq = (qrow < 49 ? 0 : (qrow < 53 ? 1 : 2)) * 3 + (qcol < 49 ? 0 : (qcol < 53 ? 1 : 2));
            int lk = (krow < 49 ? 0 : (krow < 53 ? 1 : 2)) * 3 + (kcol < 49 ? 0 : (kcol < 53 ? 1 : 2));
            if (lq != lk) acc -= 100.0f;
            s[idx] = acc;
        }
        __syncthreads();
        // softmax per row
        if (tid < L2) {
            float mx = -1e30f;
            for (int k = 0; k < L2; ++k) mx = fmaxf(mx, s[tid * L2 + k]);
            float sum = 0.f;
            for (int k = 0; k < L2; ++k) { float e = expf(s[tid * L2 + k] - mx); s[tid * L2 + k] = e; sum += e; }
            float inv = 1.0f / sum;
            for (int k = 0; k < L2; ++k) s[tid * L2 + k] *= inv;
        }
        __syncthreads();
        // o_h = s @ v
        for (int idx = tid; idx < L2 * Dh; idx += NT) {
            int t = idx / Dh, d = idx - t * Dh;
            float acc = 0.f;
            for (int k = 0; k < L2; ++k)
                acc += s[t * L2 + k] * qkv[k * 288 + 2 * C + h * Dh + d];
            osm[t * C + h * Dh + d] = acc;
        }
        __syncthreads();
    }

    // ---- proj: [49,96] @ [96,96]; write into qkv buffer (reused) ----------
    if (tid < 168) {
        int tt = tid / 24, og = tid - tt * 24;     // tt in [0,7), og in [0,24)
        int o0 = og * 4, t0 = tt * 7;
        float acc[7][4];
        #pragma unroll
        for (int a = 0; a < 7; ++a)
            for (int d = 0; d < 4; ++d) acc[a][d] = proj_b[o0 + d];
        for (int c = 0; c < C; ++c) {
            float4 wv = *(const float4*)&proj_w[c * C + o0];
            #pragma unroll
            for (int a = 0; a < 7; ++a) {
                float xv = osm[(t0 + a) * C + c];
                acc[a][0] += xv * wv.x; acc[a][1] += xv * wv.y;
                acc[a][2] += xv * wv.z; acc[a][3] += xv * wv.w;
            }
        }
        #pragma unroll
        for (int a = 0; a < 7; ++a)
            for (int d = 0; d < 4; ++d) qkv[(t0 + a) * C + o0 + d] = acc[a][d];
    }
    __syncthreads();

    // ---- scatter back (window reverse + roll) with residual ---------------
    for (int idx = tid; idx < L2 * C; idx += NT) {
        int t = idx / C, c = idx - t * C;
        int i = t / WS, j = t - i * WS;
        int row = wh * WS + i + 3; if (row >= HH) row -= HH;
        int col = ww * WS + j + 3; if (col >= HH) col -= HH;
        size_t gi = ((size_t)b * HW + row * HH + col) * C + c;
        out[gi] = x[gi] + qkv[t * C + c];
    }
}

// ---------------------------------------------------------------------------
// Kernel 2: LN2 + MLP (96->96 GELU 96->96) + residual, in-place on `out`.
// 64 tokens per block, token-disjoint so in-place is safe.
// ---------------------------------------------------------------------------
__global__ __launch_bounds__(256) void mlp_kernel(
    float* __restrict__ xio,
    const float* __restrict__ ln2_g, const float* __restrict__ ln2_b,
    const float* __restrict__ w1, const float* __restrict__ b1v,
    const float* __restrict__ w2, const float* __restrict__ b2v)
{
    __shared__ float xln[64 * 96];
    __shared__ float y1[64 * 96];
    __shared__ float mu[64], rs[64];
    __shared__ float g[96], bb[96], bias1[96], bias2[96];

    const int tid = threadIdx.x;
    const size_t tok0 = (size_t)blockIdx.x * 64;

    if (tid < 96) { g[tid] = ln2_g[tid]; bb[tid] = ln2_b[tid]; bias1[tid] = b1v[tid]; bias2[tid] = b2v[tid]; }

    for (int idx = tid; idx < 64 * 96; idx += 256) xln[idx] = xio[tok0 * 96 + idx];
    __syncthreads();

    // LN2 stats: 4 threads per token, shfl-reduce
    {
        int t = tid >> 2, part = tid & 3;
        float sum = 0.f, sq = 0.f;
        for (int c = part * 24; c < part * 24 + 24; ++c) { float v = xln[t * 96 + c]; sum += v; sq += v * v; }
        sum += __shfl_xor(sum, 1); sq += __shfl_xor(sq, 1);
        sum += __shfl_xor(sum, 2); sq += __shfl_xor(sq, 2);
        if (part == 0) {
            float m = sum * (1.0f / 96.0f);
            mu[t] = m;
            rs[t] = rsqrtf(sq * (1.0f / 96.0f) - m * m + 1e-5f);
        }
    }
    __syncthreads();
    for (int idx = tid; idx < 64 * 96; idx += 256) {
        int t = idx / 96, c = idx - t * 96;
        xln[idx] = (xln[idx] - mu[t]) * rs[t] * g[c] + bb[c];
    }
    __syncthreads();

    // GEMM1 + exact GELU: 8 tok x 4 out per thread (192 threads active)
    if (tid < 192) {
        int tt = tid / 24, og = tid - tt * 24;
        int t0 = tt * 8, o0 = og * 4;
        float acc[8][4];
        #pragma unroll
        for (int a = 0; a < 8; ++a)
            for (int d = 0; d < 4; ++d) acc[a][d] = bias1[o0 + d];
        for (int c = 0; c < 96; ++c) {
            float4 wv = *(const float4*)&w1[c * 96 + o0];
            #pragma unroll
            for (int a = 0; a < 8; ++a) {
                float xv = xln[(t0 + a) * 96 + c];
                acc[a][0] += xv * wv.x; acc[a][1] += xv * wv.y;
                acc[a][2] += xv * wv.z; acc[a][3] += xv * wv.w;
            }
        }
        #pragma unroll
        for (int a = 0; a < 8; ++a)
            for (int d = 0; d < 4; ++d) {
                float v = acc[a][d];
                v = 0.5f * v * (1.0f + erff(v * 0.70710678118654752f));
                y1[(t0 + a) * 96 + o0 + d] = v;
            }
    }
    __syncthreads();

    // GEMM2 + residual (read-modify-write own tokens; block-disjoint)
    if (tid < 192) {
        int tt = tid / 24, og = tid - tt * 24;
        int t0 = tt * 8, o0 = og * 4;
        float acc[8][4];
        #pragma unroll
        for (int a = 0; a < 8; ++a)
            for (int d = 0; d < 4; ++d) acc[a][d] = bias2[o0 + d];
        for (int c = 0; c < 96; ++c) {
            float4 wv = *(const float4*)&w2[c * 96 + o0];
            #pragma unroll
            for (int a = 0; a < 8; ++a) {
                float xv = y1[(t0 + a) * 96 + c];
                acc[a][0] += xv * wv.x; acc[a][1] += xv * wv.y;
                acc[a][2] += xv * wv.z; acc[a][3] += xv * wv.w;
            }
        }
        #pragma unroll
        for (int a = 0; a < 8; ++a)
            for (int d = 0; d < 4; ++d) {
                size_t gi = (tok0 + t0 + a) * 96 + o0 + d;
                xio[gi] = xio[gi] + acc[a][d];
            }
    }
}

extern "C" void kernel_launch(void* const* d_in, const int* in_sizes, int n_in,
                              void* d_out, int out_size, void* d_ws, size_t ws_size,
                              hipStream_t stream) {
    (void)in_sizes; (void)n_in; (void)d_ws; (void)ws_size; (void)out_size;
    const float* x         = (const float*)d_in[0];
    const float* qkv_w     = (const float*)d_in[1];
    const float* qkv_b     = (const float*)d_in[2];
    const float* attn_bias = (const float*)d_in[3];
    const float* proj_w    = (const float*)d_in[4];
    const float* proj_b    = (const float*)d_in[5];
    const float* ln1_g     = (const float*)d_in[6];
    const float* ln1_b     = (const float*)d_in[7];
    const float* ln2_g     = (const float*)d_in[8];
    const float* ln2_b     = (const float*)d_in[9];
    const float* mlp_w1    = (const float*)d_in[10];
    const float* mlp_b1    = (const float*)d_in[11];
    const float* mlp_w2    = (const float*)d_in[12];
    const float* mlp_b2    = (const float*)d_in[13];
    float* out = (float*)d_out;

    attn_kernel<<<64 * NWIN, NT, 0, stream>>>(x, qkv_w, qkv_b, attn_bias,
                                              proj_w, proj_b, ln1_g, ln1_b, out);
    mlp_kernel<<<HW, 256, 0, stream>>>(out, ln2_g, ln2_b, mlp_w1, mlp_b1, mlp_w2, mlp_b2);
}

// Round 2
// 525.590 us; speedup vs baseline: 1.8666x; 1.8666x over previous
//
#include <hip/hip_runtime.h>
#include <math.h>

constexpr int C    = 96;
constexpr int L2   = 49;
constexpr int NH   = 3;
constexpr int Dh   = 32;
constexpr int WS   = 7;
constexpr int HH   = 56;
constexpr int HW   = 3136;
constexpr int NT   = 512;

// ---- LDS layout (bytes). Regions alias where lifetimes are disjoint. ----
constexpr int XW_STRIDE = 100;   // f32 elems per token row (pad 96->100)
constexpr int Q_STRIDE  = 34;    // u16 (bf16) per token row
constexpr int KT_HSTR   = 1680;  // u16 per head for K^T [32][52] + 16 pad
constexpr int KT_STRIDE = 52;    // u16, k-contiguous rows
constexpr int V_STRIDE  = 32;    // u16
constexpr int OSM_STRIDE= 100;   // f32

constexpr int XW_OFF  = 0;                 // f32 [49][100]        = 19600
constexpr int QB_OFF  = 19600;             // u16 [3][49][34]      =  9996 (pad to 10000)
constexpr int KT_OFF  = 29600;             // u16 3*1680           = 10080 -> ends 39680
constexpr int OSM_OFF = 19600;             // f32 [49][100] 19600  (alias Q+KT, dead after scores)
constexpr int V_OFF   = 39680;             // u16 [3][49][32]      =  9408 -> ends 49088
constexpr int S_OFF   = 49088;             // f32 [3][49][49]      = 28812 -> ends 77900
constexpr int PO_OFF  = 49088;             // f32 [49][96] 18816   (alias S, dead after AV)
constexpr int SMEM_BYTES = 77904;

__device__ __forceinline__ unsigned short f2bf(float f) {
    union { float f; unsigned int u; } v; v.f = f;
    unsigned int r = v.u + 0x7fffu + ((v.u >> 16) & 1u);   // RNE
    return (unsigned short)(r >> 16);
}
__device__ __forceinline__ float bf2f(unsigned short s) {
    union { unsigned int u; float f; } v; v.u = ((unsigned int)s) << 16;
    return v.f;
}
__device__ __forceinline__ int lab(int v) { return v < 49 ? 0 : (v < 53 ? 1 : 2); }

// ---------------------------------------------------------------------------
// Kernel 1: per-window fused gather -> LN1 -> QKV(bf16 store) -> scores(all
// heads, 7x7 reg tiles) -> softmax -> AV -> proj -> scatter(+residual)
// ---------------------------------------------------------------------------
__global__ __launch_bounds__(NT, 4) void attn_kernel(
    const float* __restrict__ x,
    const float* __restrict__ qkv_w,
    const float* __restrict__ qkv_b,
    const float* __restrict__ attn_bias,
    const float* __restrict__ proj_w,
    const float* __restrict__ proj_b,
    const float* __restrict__ ln1_g,
    const float* __restrict__ ln1_b,
    float* __restrict__ out)
{
    __shared__ __align__(16) char smem[SMEM_BYTES];
    __shared__ float mu[L2], rs[L2], g1[C], b1[C];

    float*          xw   = (float*)(smem + XW_OFF);
    unsigned short* Qb   = (unsigned short*)(smem + QB_OFF);
    unsigned short* KTb  = (unsigned short*)(smem + KT_OFF);
    unsigned short* Vb   = (unsigned short*)(smem + V_OFF);
    float*          sbuf = (float*)(smem + S_OFF);
    float*          osm  = (float*)(smem + OSM_OFF);
    float*          po   = (float*)(smem + PO_OFF);

    const int blk = blockIdx.x;
    const int b   = blk >> 6;
    const int w   = blk & 63;
    const int wh  = w >> 3, ww = w & 7;
    const int tid = threadIdx.x;

    if (tid < C) { g1[tid] = ln1_g[tid]; b1[tid] = ln1_b[tid]; }

    // ---- gather window (rolled) as float4 ----
    for (int idx = tid; idx < L2 * 24; idx += NT) {
        int t = idx / 24, c4 = idx - t * 24;
        int i = t / WS, j = t - i * WS;
        int row = wh * WS + i + 3; if (row >= HH) row -= HH;
        int col = ww * WS + j + 3; if (col >= HH) col -= HH;
        float4 v = *(const float4*)&x[(((size_t)b * HW + row * HH + col) * C) + c4 * 4];
        *(float4*)&xw[t * XW_STRIDE + c4 * 4] = v;
    }
    __syncthreads();

    // ---- LN1 stats: 4 threads per token ----
    if (tid < 196) {
        int t = tid >> 2, part = tid & 3;
        float sum = 0.f, sq = 0.f;
        #pragma unroll
        for (int i = 0; i < 24; ++i) {
            float v = xw[t * XW_STRIDE + part * 24 + i];
            sum += v; sq += v * v;
        }
        sum += __shfl_xor(sum, 1); sq += __shfl_xor(sq, 1);
        sum += __shfl_xor(sum, 2); sq += __shfl_xor(sq, 2);
        if (part == 0) {
            float m = sum * (1.0f / C);
            mu[t] = m;
            rs[t] = rsqrtf(sq * (1.0f / C) - m * m + 1e-5f);
        }
    }
    __syncthreads();
    // ---- normalize in place ----
    for (int idx = tid; idx < L2 * C; idx += NT) {
        int t = idx / C, c = idx - t * C;
        float* p = &xw[t * XW_STRIDE + c];
        *p = (*p - mu[t]) * rs[t] * g1[c] + b1[c];
    }
    __syncthreads();

    // ---- QKV GEMM [49x96]@[96x288], 7tok x 4out tiles; bf16 stores ----
    if (tid < 504) {
        int tt = tid / 72, og = tid - tt * 72;
        int o0 = og * 4, t0 = tt * 7;
        float acc[7][4];
        #pragma unroll
        for (int a = 0; a < 7; ++a)
            #pragma unroll
            for (int d = 0; d < 4; ++d) acc[a][d] = qkv_b[o0 + d];
        for (int c = 0; c < C; ++c) {
            float4 wv = *(const float4*)&qkv_w[c * 288 + o0];
            #pragma unroll
            for (int a = 0; a < 7; ++a) {
                float xv = xw[(t0 + a) * XW_STRIDE + c];
                acc[a][0] += xv * wv.x; acc[a][1] += xv * wv.y;
                acc[a][2] += xv * wv.z; acc[a][3] += xv * wv.w;
            }
        }
        int kind = o0 / 96, rem = o0 - kind * 96;
        int hh = rem >> 5, dd = rem & 31;
        #pragma unroll
        for (int a = 0; a < 7; ++a) {
            int t = t0 + a;
            #pragma unroll
            for (int d = 0; d < 4; ++d) {
                unsigned short us = f2bf(acc[a][d]);
                if (kind == 0)      Qb [hh * (L2 * Q_STRIDE) + t * Q_STRIDE + dd + d] = us;
                else if (kind == 1) KTb[hh * KT_HSTR + (dd + d) * KT_STRIDE + t]      = us;
                else                Vb [hh * (L2 * V_STRIDE) + t * V_STRIDE + dd + d] = us;
            }
        }
    }
    __syncthreads();

    // ---- scores: all heads, 7q x 7k register tiles (147 threads) ----
    const float scale = 0.17677669529663687f;
    if (tid < 147) {
        int h = tid / 49, rem = tid - h * 49;
        int qg = rem / 7, kg = rem - qg * 7;
        int q0 = qg * 7, k0 = kg * 7;
        float acc[7][7];
        #pragma unroll
        for (int i = 0; i < 7; ++i)
            #pragma unroll
            for (int j = 0; j < 7; ++j) acc[i][j] = 0.f;
        const unsigned short* qp = Qb + h * (L2 * Q_STRIDE) + q0 * Q_STRIDE;
        const unsigned short* kp = KTb + h * KT_HSTR + k0;
        for (int d = 0; d < Dh; ++d) {
            float qv[7], kv[7];
            #pragma unroll
            for (int i = 0; i < 7; ++i) qv[i] = bf2f(qp[i * Q_STRIDE + d]);
            #pragma unroll
            for (int j = 0; j < 7; ++j) kv[j] = bf2f(kp[d * KT_STRIDE + j]);
            #pragma unroll
            for (int i = 0; i < 7; ++i)
                #pragma unroll
                for (int j = 0; j < 7; ++j) acc[i][j] += qv[i] * kv[j];
        }
        int qrl = lab(wh * WS + qg), krl = lab(wh * WS + kg);
        int cl[7];
        #pragma unroll
        for (int v = 0; v < 7; ++v) cl[v] = lab(ww * WS + v);
        const float* bp = attn_bias + (h * L2 + q0) * L2 + k0;
        #pragma unroll
        for (int i = 0; i < 7; ++i) {
            #pragma unroll
            for (int j = 0; j < 7; ++j) {
                float val = acc[i][j] * scale + bp[i * L2 + j];
                if (qrl != krl || cl[i] != cl[j]) val -= 100.0f;
                sbuf[(h * L2 + q0 + i) * L2 + k0 + j] = val;
            }
        }
    }
    __syncthreads();

    // ---- softmax: 2 threads per row, 147 rows ----
    if (tid < 294) {
        int r = tid >> 1, part = tid & 1;
        float* row = sbuf + r * L2;
        int kb = part * 25, ke = part ? 49 : 25;
        float mx = -1e30f;
        for (int k = kb; k < ke; ++k) mx = fmaxf(mx, row[k]);
        mx = fmaxf(mx, __shfl_xor(mx, 1));
        float sum = 0.f;
        for (int k = kb; k < ke; ++k) { float e = __expf(row[k] - mx); row[k] = e; sum += e; }
        sum += __shfl_xor(sum, 1);
        float inv = 1.0f / sum;
        for (int k = kb; k < ke; ++k) row[k] *= inv;
    }
    __syncthreads();

    // ---- AV: 7q x 4d tiles, all heads (168 threads) ----
    if (tid < 168) {
        int h = tid / 56, rem = tid - h * 56;
        int qg = rem >> 3, dg = rem & 7;
        int q0 = qg * 7, d0 = dg * 4;
        float acc[7][4];
        #pragma unroll
        for (int i = 0; i < 7; ++i)
            #pragma unroll
            for (int d = 0; d < 4; ++d) acc[i][d] = 0.f;
        const unsigned short* vp = Vb + h * (L2 * V_STRIDE) + d0;
        const float* sp = sbuf + (h * L2 + q0) * L2;
        for (int k = 0; k < L2; ++k) {
            uint2 vv = *(const uint2*)&vp[k * V_STRIDE];
            float v0 = __uint_as_float(vv.x << 16);
            float v1 = __uint_as_float(vv.x & 0xffff0000u);
            float v2 = __uint_as_float(vv.y << 16);
            float v3 = __uint_as_float(vv.y & 0xffff0000u);
            #pragma unroll
            for (int i = 0; i < 7; ++i) {
                float s = sp[i * L2 + k];
                acc[i][0] += s * v0; acc[i][1] += s * v1;
                acc[i][2] += s * v2; acc[i][3] += s * v3;
            }
        }
        #pragma unroll
        for (int i = 0; i < 7; ++i)
            *(float4*)&osm[(q0 + i) * OSM_STRIDE + h * Dh + d0] =
                make_float4(acc[i][0], acc[i][1], acc[i][2], acc[i][3]);
    }
    __syncthreads();

    // ---- proj [49x96]@[96x96]: 7tok x 2out tiles (336 threads) ----
    if (tid < 336) {
        int tt = tid / 48, og = tid - tt * 48;
        int t0 = tt * 7, o0 = og * 2;
        float acc[7][2];
        #pragma unroll
        for (int a = 0; a < 7; ++a) { acc[a][0] = proj_b[o0]; acc[a][1] = proj_b[o0 + 1]; }
        for (int c = 0; c < C; ++c) {
            float2 wv = *(const float2*)&proj_w[c * C + o0];
            #pragma unroll
            for (int a = 0; a < 7; ++a) {
                float xv = osm[(t0 + a) * OSM_STRIDE + c];
                acc[a][0] += xv * wv.x; acc[a][1] += xv * wv.y;
            }
        }
        #pragma unroll
        for (int a = 0; a < 7; ++a)
            *(float2*)&po[(t0 + a) * C + o0] = make_float2(acc[a][0], acc[a][1]);
    }
    __syncthreads();

    // ---- scatter (window reverse + roll) + residual, float4 ----
    for (int idx = tid; idx < L2 * 24; idx += NT) {
        int t = idx / 24, c4 = idx - t * 24;
        int i = t / WS, j = t - i * WS;
        int row = wh * WS + i + 3; if (row >= HH) row -= HH;
        int col = ww * WS + j + 3; if (col >= HH) col -= HH;
        size_t gbase = (((size_t)b * HW + row * HH + col) * C) + c4 * 4;
        float4 pv = *(float4*)&po[t * C + c4 * 4];
        float4 xv = *(const float4*)&x[gbase];
        float4 o;
        o.x = xv.x + pv.x; o.y = xv.y + pv.y; o.z = xv.z + pv.z; o.w = xv.w + pv.w;
        *(float4*)&out[gbase] = o;
    }
}

// ---------------------------------------------------------------------------
// Kernel 2: LN2 + MLP + residual, in-place on `out` (token-disjoint blocks).
// ---------------------------------------------------------------------------
__global__ __launch_bounds__(256) void mlp_kernel(
    float* __restrict__ xio,
    const float* __restrict__ ln2_g, const float* __restrict__ ln2_b,
    const float* __restrict__ w1, const float* __restrict__ b1v,
    const float* __restrict__ w2, const float* __restrict__ b2v)
{
    __shared__ float xln[64 * 96];
    __shared__ float y1[64 * 96];
    __shared__ float mu[64], rs[64];
    __shared__ float g[96], bb[96], bias1[96], bias2[96];

    const int tid = threadIdx.x;
    const size_t tok0 = (size_t)blockIdx.x * 64;

    if (tid < 96) { g[tid] = ln2_g[tid]; bb[tid] = ln2_b[tid]; bias1[tid] = b1v[tid]; bias2[tid] = b2v[tid]; }

    for (int idx = tid; idx < 64 * 96; idx += 256) xln[idx] = xio[tok0 * 96 + idx];
    __syncthreads();

    {
        int t = tid >> 2, part = tid & 3;
        float sum = 0.f, sq = 0.f;
        for (int c = part * 24; c < part * 24 + 24; ++c) { float v = xln[t * 96 + c]; sum += v; sq += v * v; }
        sum += __shfl_xor(sum, 1); sq += __shfl_xor(sq, 1);
        sum += __shfl_xor(sum, 2); sq += __shfl_xor(sq, 2);
        if (part == 0) {
            float m = sum * (1.0f / 96.0f);
            mu[t] = m;
            rs[t] = rsqrtf(sq * (1.0f / 96.0f) - m * m + 1e-5f);
        }
    }
    __syncthreads();
    for (int idx = tid; idx < 64 * 96; idx += 256) {
        int t = idx / 96, c = idx - t * 96;
        xln[idx] = (xln[idx] - mu[t]) * rs[t] * g[c] + bb[c];
    }
    __syncthreads();

    if (tid < 192) {
        int tt = tid / 24, og = tid - tt * 24;
        int t0 = tt * 8, o0 = og * 4;
        float acc[8][4];
        #pragma unroll
        for (int a = 0; a < 8; ++a)
            #pragma unroll
            for (int d = 0; d < 4; ++d) acc[a][d] = bias1[o0 + d];
        for (int c = 0; c < 96; ++c) {
            float4 wv = *(const float4*)&w1[c * 96 + o0];
            #pragma unroll
            for (int a = 0; a < 8; ++a) {
                float xv = xln[(t0 + a) * 96 + c];
                acc[a][0] += xv * wv.x; acc[a][1] += xv * wv.y;
                acc[a][2] += xv * wv.z; acc[a][3] += xv * wv.w;
            }
        }
        #pragma unroll
        for (int a = 0; a < 8; ++a)
            #pragma unroll
            for (int d = 0; d < 4; ++d) {
                float v = acc[a][d];
                v = 0.5f * v * (1.0f + erff(v * 0.70710678118654752f));
                y1[(t0 + a) * 96 + o0 + d] = v;
            }
    }
    __syncthreads();

    if (tid < 192) {
        int tt = tid / 24, og = tid - tt * 24;
        int t0 = tt * 8, o0 = og * 4;
        float acc[8][4];
        #pragma unroll
        for (int a = 0; a < 8; ++a)
            #pragma unroll
            for (int d = 0; d < 4; ++d) acc[a][d] = bias2[o0 + d];
        for (int c = 0; c < 96; ++c) {
            float4 wv = *(const float4*)&w2[c * 96 + o0];
            #pragma unroll
            for (int a = 0; a < 8; ++a) {
                float xv = y1[(t0 + a) * 96 + c];
                acc[a][0] += xv * wv.x; acc[a][1] += xv * wv.y;
                acc[a][2] += xv * wv.z; acc[a][3] += xv * wv.w;
            }
        }
        #pragma unroll
        for (int a = 0; a < 8; ++a)
            #pragma unroll
            for (int d = 0; d < 4; ++d) {
                size_t gi = (tok0 + t0 + a) * 96 + o0 + d;
                xio[gi] = xio[gi] + acc[a][d];
            }
    }
}

extern "C" void kernel_launch(void* const* d_in, const int* in_sizes, int n_in,
                              void* d_out, int out_size, void* d_ws, size_t ws_size,
                              hipStream_t stream) {
    (void)in_sizes; (void)n_in; (void)d_ws; (void)ws_size; (void)out_size;
    const float* x         = (const float*)d_in[0];
    const float* qkv_w     = (const float*)d_in[1];
    const float* qkv_b     = (const float*)d_in[2];
    const float* attn_bias = (const float*)d_in[3];
    const float* proj_w    = (const float*)d_in[4];
    const float* proj_b    = (const float*)d_in[5];
    const float* ln1_g     = (const float*)d_in[6];
    const float* ln1_b     = (const float*)d_in[7];
    const float* ln2_g     = (const float*)d_in[8];
    const float* ln2_b     = (const float*)d_in[9];
    const float* mlp_w1    = (const float*)d_in[10];
    const float* mlp_b1    = (const float*)d_in[11];
    const float* mlp_w2    = (const float*)d_in[12];
    const float* mlp_b2    = (const float*)d_in[13];
    float* out = (float*)d_out;

    attn_kernel<<<64 * 64, NT, 0, stream>>>(x, qkv_w, qkv_b, attn_bias,
                                            proj_w, proj_b, ln1_g, ln1_b, out);
    mlp_kernel<<<HW, 256, 0, stream>>>(out, ln2_g, ln2_b, mlp_w1, mlp_b1, mlp_w2, mlp_b2);
}

// Round 6
// 263.421 us; speedup vs baseline: 3.7244x; 1.9952x over previous
//
#include <hip/hip_runtime.h>
#include <math.h>

typedef _Float16 half8 __attribute__((ext_vector_type(8)));
typedef float f32x4 __attribute__((ext_vector_type(4)));

#define MFMA_F16 __builtin_amdgcn_mfma_f32_16x16x32_f16

constexpr int WS = 7, HH = 56, HW = 3136;
constexpr int NTOK = 64 * HW;      // 200704 total tokens

// d_ws layout (fp16 element offsets)
constexpr int QKVP_OFF  = 0;       // 18nt*3kb*4ksub*16col*8 = 27648
constexpr int PROJP_OFF = 27648;   // 6*3*4*128 = 9216
constexpr int W1P_OFF   = 36864;   // 9216
constexpr int W2P_OFF   = 46080;   // 9216 -> total 55296 fp16 = 110592 B

__device__ __forceinline__ int lab3(int v) { return v < 49 ? 0 : (v < 53 ? 1 : 2); }
__device__ __forceinline__ int div7c(int v) { return (v * 9363) >> 16; }  // valid 0..63

// ---------------------------------------------------------------------------
// Weight pre-pack: f32 [K][N] row-major -> fp16 B-fragment tiles
// [nt][kb][ksub][col16][8]: elem (nt,kb,ksub,col,j) = W[kb*32+ksub*8+j][nt*16+col]
// ---------------------------------------------------------------------------
__global__ __launch_bounds__(256) void pack_w3(
    const float* __restrict__ qkv_w, const float* __restrict__ proj_w,
    const float* __restrict__ w1, const float* __restrict__ w2,
    _Float16* __restrict__ ws)
{
    int i = blockIdx.x * 256 + threadIdx.x;
    const float* src; int ncol, local;
    if (i < 27648)      { src = qkv_w;  ncol = 288; local = i; }
    else if (i < 36864) { src = proj_w; ncol = 96;  local = i - 27648; }
    else if (i < 46080) { src = w1;     ncol = 96;  local = i - 36864; }
    else                { src = w2;     ncol = 96;  local = i - 46080; }
    int j = local & 7, col = (local >> 3) & 15, ksub = (local >> 7) & 3;
    int rest = local >> 9;
    int kb = rest % 3, nt = rest / 3;
    int k = kb * 32 + ksub * 8 + j, n = nt * 16 + col;
    ws[i] = (_Float16)src[k * ncol + n];
}

// ---------------------------------------------------------------------------
// attn: gather+LN1 -> QKV (MFMA) -> scores (MFMA) -> softmax -> PV (MFMA)
//       -> proj (MFMA) -> scatter+residual.  One block per (batch, window).
// LDS byte map:
//   [0,19600)      xw f32[49][100]   (later: po f32[49][100])
//   [19600,31888)  XLN fp16 [12][64][8]     } P fp16 [3][8][64][8] aliases both
//   [31888,44176)  Q   fp16 [3][4][64][8]   }
//   [44176,56464)  K   fp16 [3][4][64][8]   (later: O fp16 [12][64][8])
//   [56464,68752)  V   fp16 [3][8][32][8]
// ---------------------------------------------------------------------------
__global__ __launch_bounds__(256, 2) void attn_k3(
    const float* __restrict__ x,
    const float* __restrict__ qkv_b,
    const float* __restrict__ attn_bias,
    const float* __restrict__ proj_b,
    const float* __restrict__ ln1_g,
    const float* __restrict__ ln1_b,
    const _Float16* __restrict__ wpack,
    float* __restrict__ out)
{
    __shared__ __align__(16) char smem[68752];
    __shared__ float mu[49], rs[49], g1[96], b1[96];

    float*     xw  = (float*)smem;
    float*     po  = (float*)smem;
    _Float16*  XLN = (_Float16*)(smem + 19600);
    _Float16*  Qu  = (_Float16*)(smem + 31888);
    _Float16*  Ku  = (_Float16*)(smem + 44176);
    _Float16*  Vu  = (_Float16*)(smem + 56464);
    _Float16*  Pu  = XLN;   // 24576 B spanning XLN+Q
    _Float16*  Ou  = Ku;

    const _Float16* qkvp  = wpack + QKVP_OFF;
    const _Float16* projp = wpack + PROJP_OFF;

    const int blk = blockIdx.x;
    const int b   = blk >> 6;
    const int w   = blk & 63;
    const int wh  = w >> 3, ww = w & 7;
    const int tid = threadIdx.x;
    const int wv  = tid >> 6, lane = tid & 63;
    const int l15 = lane & 15, l4 = lane >> 4;

    if (tid < 96) { g1[tid] = ln1_g[tid]; b1[tid] = ln1_b[tid]; }

    // ---- gather window (rolled) + zero V pad region ----
    for (int idx = tid; idx < 49 * 24; idx += 256) {
        int t = (idx * 2731) >> 16, c4 = idx - t * 24;   // t = idx/24
        int i = div7c(t), j = t - i * 7;
        int row = wh * WS + i + 3; if (row >= HH) row -= HH;
        int col = ww * WS + j + 3; if (col >= HH) col -= HH;
        *(float4*)&xw[t * 100 + c4 * 4] =
            *(const float4*)&x[(((size_t)b * HW + row * HH + col) * 96) + c4 * 4];
    }
    for (int idx = tid; idx < 768; idx += 256)           // 12288 B of V
        ((uint4*)Vu)[idx] = make_uint4(0, 0, 0, 0);
    __syncthreads();

    // ---- LN1 stats ----
    if (tid < 196) {
        int t = tid >> 2, part = tid & 3;
        float sum = 0.f, sq = 0.f;
        #pragma unroll
        for (int i = 0; i < 24; ++i) {
            float v = xw[t * 100 + part * 24 + i];
            sum += v; sq += v * v;
        }
        sum += __shfl_xor(sum, 1); sq += __shfl_xor(sq, 1);
        sum += __shfl_xor(sum, 2); sq += __shfl_xor(sq, 2);
        if (part == 0) {
            float m = sum * (1.0f / 96.0f);
            mu[t] = m;
            rs[t] = rsqrtf(sq * (1.0f / 96.0f) - m * m + 1e-5f);
        }
    }
    __syncthreads();

    // ---- normalize -> fp16 A-tiles [12][64][8] ----
    for (int idx = tid; idx < 588; idx += 256) {         // 12 chunks * 49 tok
        int chunk = (idx * 1338) >> 16;                  // idx/49
        int t = idx - chunk * 49;
        float m = mu[t], r = rs[t];
        half8 pk;
        #pragma unroll
        for (int j = 0; j < 8; ++j) {
            int c = chunk * 8 + j;
            float v = (xw[t * 100 + c] - m) * r * g1[c] + b1[c];
            pk[j] = (_Float16)v;
        }
        *(half8*)&XLN[chunk * 512 + t * 8] = pk;
    }
    __syncthreads();

    // ---- QKV GEMM: wave wv owns token tile mt=wv ----
    {
        half8 a[3];
        #pragma unroll
        for (int kb = 0; kb < 3; ++kb)
            a[kb] = *(half8*)&XLN[(kb * 4 + l4) * 512 + (wv * 16 + l15) * 8];
        for (int nt = 0; nt < 18; ++nt) {
            f32x4 acc = {0.f, 0.f, 0.f, 0.f};
            #pragma unroll
            for (int kb = 0; kb < 3; ++kb) {
                half8 bw = *(const half8*)&qkvp[((nt * 3 + kb) * 4 + l4) * 128 + l15 * 8];
                acc = MFMA_F16(a[kb], bw, acc, 0, 0, 0);
            }
            int n = nt * 16 + l15;
            float bias = qkv_b[n];
            #pragma unroll
            for (int r = 0; r < 4; ++r) {
                int tok = wv * 16 + l4 * 4 + r;
                if (tok < 49) {
                    _Float16 us = (_Float16)(acc[r] + bias);
                    if (n < 96) {
                        int h = n >> 5, d = n & 31;
                        Qu[(h * 4 + (d >> 3)) * 512 + tok * 8 + (d & 7)] = us;
                    } else if (n < 192) {
                        int m2 = n - 96, h = m2 >> 5, d = m2 & 31;
                        Ku[(h * 4 + (d >> 3)) * 512 + tok * 8 + (d & 7)] = us;
                    } else {
                        int m2 = n - 192, h = m2 >> 5, d = m2 & 31;
                        Vu[(h * 8 + (tok >> 3)) * 256 + d * 8 + (tok & 7)] = us;
                    }
                }
            }
        }
    }
    __syncthreads();

    // ---- scores: wave wv owns q-tile mtq=wv; all heads, K=32 single MFMA ----
    f32x4 s[3][4];
    #pragma unroll
    for (int h = 0; h < 3; ++h) {
        half8 qf = *(half8*)&Qu[(h * 4 + l4) * 512 + (wv * 16 + l15) * 8];
        #pragma unroll
        for (int nt = 0; nt < 4; ++nt) {
            half8 kf = *(half8*)&Ku[(h * 4 + l4) * 512 + (nt * 16 + l15) * 8];
            f32x4 z = {0.f, 0.f, 0.f, 0.f};
            s[h][nt] = MFMA_F16(qf, kf, z, 0, 0, 0);
        }
    }
    __syncthreads();   // Q,K dead; P may overwrite XLN+Q

    // ---- bias+mask+softmax (registers) -> P fp16 tiles ----
    {
        const float scale = 0.17677669529663687f;
        int kk[4], lkr[4], lkc[4]; bool kok[4];
        #pragma unroll
        for (int nt = 0; nt < 4; ++nt) {
            int k = nt * 16 + l15;
            kk[nt] = k; kok[nt] = (k < 49);
            int ki = div7c(k), kj = k - ki * 7;
            lkr[nt] = lab3(wh * WS + ki);
            lkc[nt] = lab3(ww * WS + kj);
        }
        #pragma unroll
        for (int h = 0; h < 3; ++h) {
            #pragma unroll
            for (int r = 0; r < 4; ++r) {
                int q = wv * 16 + l4 * 4 + r;
                bool qo = (q < 49);
                int qi = div7c(q), qj = q - qi * 7;
                int lqr = lab3(wh * WS + qi), lqc = lab3(ww * WS + qj);
                float vals[4];
                #pragma unroll
                for (int nt = 0; nt < 4; ++nt) {
                    float v;
                    if (qo && kok[nt]) {
                        v = s[h][nt][r] * scale + attn_bias[(h * 49 + q) * 49 + kk[nt]];
                        if (lqr != lkr[nt] || lqc != lkc[nt]) v -= 100.0f;
                    } else v = -30000.0f;
                    vals[nt] = v;
                }
                float mx = fmaxf(fmaxf(vals[0], vals[1]), fmaxf(vals[2], vals[3]));
                mx = fmaxf(mx, __shfl_xor(mx, 1));
                mx = fmaxf(mx, __shfl_xor(mx, 2));
                mx = fmaxf(mx, __shfl_xor(mx, 4));
                mx = fmaxf(mx, __shfl_xor(mx, 8));
                float e[4], sum = 0.f;
                #pragma unroll
                for (int nt = 0; nt < 4; ++nt) { e[nt] = __expf(vals[nt] - mx); sum += e[nt]; }
                sum += __shfl_xor(sum, 1);
                sum += __shfl_xor(sum, 2);
                sum += __shfl_xor(sum, 4);
                sum += __shfl_xor(sum, 8);
                float inv = 1.0f / sum;
                #pragma unroll
                for (int nt = 0; nt < 4; ++nt)
                    Pu[(h * 8 + (kk[nt] >> 3)) * 512 + q * 8 + (kk[nt] & 7)] = (_Float16)(e[nt] * inv);
            }
        }
    }
    // no sync: PV reads only this wave's own P rows; O overwrites K (dead for all)

    // ---- PV: wave wv owns q-tile; O = P @ V, write fp16 A-tiles ----
    #pragma unroll
    for (int h = 0; h < 3; ++h) {
        half8 pa0 = *(half8*)&Pu[(h * 8 + 0 + l4) * 512 + (wv * 16 + l15) * 8];
        half8 pa1 = *(half8*)&Pu[(h * 8 + 4 + l4) * 512 + (wv * 16 + l15) * 8];
        #pragma unroll
        for (int ntd = 0; ntd < 2; ++ntd) {
            f32x4 acc = {0.f, 0.f, 0.f, 0.f};
            half8 vb0 = *(half8*)&Vu[(h * 8 + 0 + l4) * 256 + (ntd * 16 + l15) * 8];
            acc = MFMA_F16(pa0, vb0, acc, 0, 0, 0);
            half8 vb1 = *(half8*)&Vu[(h * 8 + 4 + l4) * 256 + (ntd * 16 + l15) * 8];
            acc = MFMA_F16(pa1, vb1, acc, 0, 0, 0);
            int c = h * 32 + ntd * 16 + l15;
            #pragma unroll
            for (int r = 0; r < 4; ++r) {
                int tok = wv * 16 + l4 * 4 + r;
                Ou[(c >> 3) * 512 + tok * 8 + (c & 7)] = (_Float16)acc[r];
            }
        }
    }
    // no sync: proj reads only this wave's own O rows

    // ---- proj: [49x96]@[96x96] -> po f32 staging ----
    {
        half8 oa[3];
        #pragma unroll
        for (int kb = 0; kb < 3; ++kb)
            oa[kb] = *(half8*)&Ou[(kb * 4 + l4) * 512 + (wv * 16 + l15) * 8];
        for (int nt = 0; nt < 6; ++nt) {
            f32x4 acc = {0.f, 0.f, 0.f, 0.f};
            #pragma unroll
            for (int kb = 0; kb < 3; ++kb) {
                half8 bw = *(const half8*)&projp[((nt * 3 + kb) * 4 + l4) * 128 + l15 * 8];
                acc = MFMA_F16(oa[kb], bw, acc, 0, 0, 0);
            }
            int n = nt * 16 + l15;
            float pb = proj_b[n];
            #pragma unroll
            for (int r = 0; r < 4; ++r) {
                int tok = wv * 16 + l4 * 4 + r;
                if (tok < 49) po[tok * 100 + n] = acc[r] + pb;
            }
        }
    }
    __syncthreads();

    // ---- scatter + residual ----
    for (int idx = tid; idx < 49 * 24; idx += 256) {
        int t = (idx * 2731) >> 16, c4 = idx - t * 24;
        int i = div7c(t), j = t - i * 7;
        int row = wh * WS + i + 3; if (row >= HH) row -= HH;
        int col = ww * WS + j + 3; if (col >= HH) col -= HH;
        size_t gbase = (((size_t)b * HW + row * HH + col) * 96) + c4 * 4;
        float4 pv = *(float4*)&po[t * 100 + c4 * 4];
        float4 xv = *(const float4*)&x[gbase];
        float4 o;
        o.x = xv.x + pv.x; o.y = xv.y + pv.y; o.z = xv.z + pv.z; o.w = xv.w + pv.w;
        *(float4*)&out[gbase] = o;
    }
}

// ---------------------------------------------------------------------------
// MLP: LN2 -> GEMM1(MFMA) -> GELU -> GEMM2(MFMA) + residual, in-place.
// 64 tokens/block, 256 threads, 4 waves (wave wv owns token tile mt=wv).
// Grid MUST be NTOK/64 = 3136 blocks (covers ALL B*H*W tokens).
// ---------------------------------------------------------------------------
__global__ __launch_bounds__(256, 4) void mlp_k3(
    float* __restrict__ xio,
    const float* __restrict__ ln2_g, const float* __restrict__ ln2_b,
    const float* __restrict__ b1v, const float* __restrict__ b2v,
    const _Float16* __restrict__ wpack)
{
    __shared__ _Float16 xln[12 * 520];
    __shared__ _Float16 yb[12 * 520];
    __shared__ float mu[64], rs[64], g[96], bb[96], bi1[96], bi2[96];

    const _Float16* w1p = wpack + W1P_OFF;
    const _Float16* w2p = wpack + W2P_OFF;

    const int tid = threadIdx.x;
    const int wv  = tid >> 6, lane = tid & 63;
    const int l15 = lane & 15, l4 = lane >> 4;
    const size_t tok0 = (size_t)blockIdx.x * 64;

    if (tid < 96) { g[tid] = ln2_g[tid]; bb[tid] = ln2_b[tid]; bi1[tid] = b1v[tid]; bi2[tid] = b2v[tid]; }

    // ---- LN2 stats: 4 threads/token ----
    {
        int t = tid >> 2, part = tid & 3;
        const float* xp = xio + (tok0 + t) * 96 + part * 24;
        float sum = 0.f, sq = 0.f;
        #pragma unroll
        for (int i = 0; i < 6; ++i) {
            float4 v = *(const float4*)&xp[i * 4];
            sum += v.x + v.y + v.z + v.w;
            sq  += v.x * v.x + v.y * v.y + v.z * v.z + v.w * v.w;
        }
        sum += __shfl_xor(sum, 1); sq += __shfl_xor(sq, 1);
        sum += __shfl_xor(sum, 2); sq += __shfl_xor(sq, 2);
        if (part == 0) {
            float m = sum * (1.0f / 96.0f);
            mu[t] = m;
            rs[t] = rsqrtf(sq * (1.0f / 96.0f) - m * m + 1e-5f);
        }
    }
    __syncthreads();

    // ---- normalize -> fp16 A-tiles ----
    for (int idx = tid; idx < 768; idx += 256) {
        int t = idx & 63, chunk = idx >> 6;
        float m = mu[t], r = rs[t];
        const float* xp = &xio[(tok0 + t) * 96 + chunk * 8];
        half8 pk;
        #pragma unroll
        for (int j = 0; j < 8; ++j) {
            int c = chunk * 8 + j;
            pk[j] = (_Float16)((xp[j] - m) * r * g[c] + bb[c]);
        }
        *(half8*)&xln[chunk * 520 + t * 8] = pk;
    }
    __syncthreads();

    // ---- GEMM1 + GELU ----
    {
        half8 a[3];
        #pragma unroll
        for (int kb = 0; kb < 3; ++kb)
            a[kb] = *(half8*)&xln[(kb * 4 + l4) * 520 + (wv * 16 + l15) * 8];
        for (int nt = 0; nt < 6; ++nt) {
            f32x4 acc = {0.f, 0.f, 0.f, 0.f};
            #pragma unroll
            for (int kb = 0; kb < 3; ++kb) {
                half8 bw = *(const half8*)&w1p[((nt * 3 + kb) * 4 + l4) * 128 + l15 * 8];
                acc = MFMA_F16(a[kb], bw, acc, 0, 0, 0);
            }
            int n = nt * 16 + l15;
            float bias = bi1[n];
            #pragma unroll
            for (int r = 0; r < 4; ++r) {
                int tok = wv * 16 + l4 * 4 + r;
                float v = acc[r] + bias;
                v = 0.5f * v * (1.0f + erff(v * 0.70710678118654752f));
                yb[(n >> 3) * 520 + tok * 8 + (n & 7)] = (_Float16)v;
            }
        }
    }
    __syncthreads();

    // ---- GEMM2 + residual ----
    {
        half8 a[3];
        #pragma unroll
        for (int kb = 0; kb < 3; ++kb)
            a[kb] = *(half8*)&yb[(kb * 4 + l4) * 520 + (wv * 16 + l15) * 8];
        for (int nt = 0; nt < 6; ++nt) {
            f32x4 acc = {0.f, 0.f, 0.f, 0.f};
            #pragma unroll
            for (int kb = 0; kb < 3; ++kb) {
                half8 bw = *(const half8*)&w2p[((nt * 3 + kb) * 4 + l4) * 128 + l15 * 8];
                acc = MFMA_F16(a[kb], bw, acc, 0, 0, 0);
            }
            int n = nt * 16 + l15;
            float bias = bi2[n];
            #pragma unroll
            for (int r = 0; r < 4; ++r) {
                int tok = wv * 16 + l4 * 4 + r;
                size_t gi = (tok0 + tok) * 96 + n;
                xio[gi] = xio[gi] + acc[r] + bias;
            }
        }
    }
}

extern "C" void kernel_launch(void* const* d_in, const int* in_sizes, int n_in,
                              void* d_out, int out_size, void* d_ws, size_t ws_size,
                              hipStream_t stream) {
    (void)in_sizes; (void)n_in; (void)ws_size; (void)out_size;
    const float* x         = (const float*)d_in[0];
    const float* qkv_w     = (const float*)d_in[1];
    const float* qkv_b     = (const float*)d_in[2];
    const float* attn_bias = (const float*)d_in[3];
    const float* proj_w    = (const float*)d_in[4];
    const float* proj_b    = (const float*)d_in[5];
    const float* ln1_g     = (const float*)d_in[6];
    const float* ln1_b     = (const float*)d_in[7];
    const float* ln2_g     = (const float*)d_in[8];
    const float* ln2_b     = (const float*)d_in[9];
    const float* mlp_w1    = (const float*)d_in[10];
    const float* mlp_b1    = (const float*)d_in[11];
    const float* mlp_w2    = (const float*)d_in[12];
    const float* mlp_b2    = (const float*)d_in[13];
    float* out = (float*)d_out;
    _Float16* wpack = (_Float16*)d_ws;

    pack_w3<<<216, 256, 0, stream>>>(qkv_w, proj_w, mlp_w1, mlp_w2, wpack);
    attn_k3<<<64 * 64, 256, 0, stream>>>(x, qkv_b, attn_bias, proj_b,
                                         ln1_g, ln1_b, wpack, out);
    mlp_k3<<<NTOK / 64, 256, 0, stream>>>(out, ln2_g, ln2_b, mlp_b1, mlp_b2, wpack);
}

// Round 7
// 226.430 us; speedup vs baseline: 4.3328x; 1.1634x over previous
//
#include <hip/hip_runtime.h>
#include <math.h>

typedef _Float16 half8 __attribute__((ext_vector_type(8)));
typedef float f32x4 __attribute__((ext_vector_type(4)));

#define MFMA_F16 __builtin_amdgcn_mfma_f32_16x16x32_f16

constexpr int WS = 7, HH = 56, HW = 3136;
constexpr int NTOK = 64 * HW;      // 200704 total tokens

// d_ws layout (fp16 element offsets)
constexpr int QKVP_OFF  = 0;       // 27648
constexpr int PROJP_OFF = 27648;   // 9216
constexpr int W1P_OFF   = 36864;   // 9216
constexpr int W2P_OFF   = 46080;   // 9216

__device__ __forceinline__ int lab4(int v) { return v < 49 ? 0 : (v < 53 ? 1 : 2); }
__device__ __forceinline__ int div7d(int v) { return (v * 9363) >> 16; }  // valid 0..63

// ---------------------------------------------------------------------------
// Weight pre-pack: f32 [K][N] row-major -> fp16 B-fragment tiles
// ---------------------------------------------------------------------------
__global__ __launch_bounds__(256) void pack_w4(
    const float* __restrict__ qkv_w, const float* __restrict__ proj_w,
    const float* __restrict__ w1, const float* __restrict__ w2,
    _Float16* __restrict__ ws)
{
    int i = blockIdx.x * 256 + threadIdx.x;
    const float* src; int ncol, local;
    if (i < 27648)      { src = qkv_w;  ncol = 288; local = i; }
    else if (i < 36864) { src = proj_w; ncol = 96;  local = i - 27648; }
    else if (i < 46080) { src = w1;     ncol = 96;  local = i - 36864; }
    else                { src = w2;     ncol = 96;  local = i - 46080; }
    int j = local & 7, col = (local >> 3) & 15, ksub = (local >> 7) & 3;
    int rest = local >> 9;
    int kb = rest % 3, nt = rest / 3;
    int k = kb * 32 + ksub * 8 + j, n = nt * 16 + col;
    ws[i] = (_Float16)src[k * ncol + n];
}

// ---------------------------------------------------------------------------
// attn: reg-gather+LN1 -> QKV (MFMA) -> scores (MFMA) -> reg softmax ->
//       PV (MFMA) -> proj (MFMA) -> direct global scatter(+residual).
// One block per (batch, window). 4 barriers. ~50 KB LDS -> 3 blocks/CU.
// LDS byte map (aliases where lifetimes are disjoint):
//   [0,12288)      XLN fp16 [12][64][8]   } Pu fp16 [3][8][64][8] spans both
//   [12288,24576)  Qu  fp16 [3][4][64][8] }
//   [24576,36864)  Ku  fp16 [3][4][64][8]   (later: Ou fp16 [12][64][8])
//   [36864,49152)  Vu  fp16 [3][8][32][8]
// ---------------------------------------------------------------------------
__global__ __launch_bounds__(256, 3) void attn_k4(
    const float* __restrict__ x,
    const float* __restrict__ qkv_b,
    const float* __restrict__ attn_bias,
    const float* __restrict__ proj_b,
    const float* __restrict__ ln1_g,
    const float* __restrict__ ln1_b,
    const _Float16* __restrict__ wpack,
    float* __restrict__ out)
{
    __shared__ __align__(16) char smem[49152];
    __shared__ float g1[96], b1[96];

    _Float16*  XLN = (_Float16*)smem;
    _Float16*  Qu  = (_Float16*)(smem + 12288);
    _Float16*  Ku  = (_Float16*)(smem + 24576);
    _Float16*  Vu  = (_Float16*)(smem + 36864);
    _Float16*  Pu  = XLN;   // 24576 B spanning XLN+Qu
    _Float16*  Ou  = Ku;

    const _Float16* qkvp  = wpack + QKVP_OFF;
    const _Float16* projp = wpack + PROJP_OFF;

    const int blk = blockIdx.x;
    const int b   = blk >> 6;
    const int w   = blk & 63;
    const int wh  = w >> 3, ww = w & 7;
    const int tid = threadIdx.x;
    const int wv  = tid >> 6, lane = tid & 63;
    const int l15 = lane & 15, l4 = lane >> 4;

    if (tid < 96) { g1[tid] = ln1_g[tid]; b1[tid] = ln1_b[tid]; }

    // ---- zero V pad region (768 * 16B = 12288B) ----
    for (int idx = tid; idx < 768; idx += 256)
        ((uint4*)Vu)[idx] = make_uint4(0, 0, 0, 0);

    // ---- gather window (rolled) into registers: 4 threads/token x 24 ch ----
    const int t_own = tid >> 2, part = tid & 3;
    const bool active = (tid < 196);
    float4 xq[6];
    float m = 0.f, rinv = 0.f;
    if (active) {
        int i = div7d(t_own), j = t_own - i * 7;
        int row = wh * WS + i + 3; if (row >= HH) row -= HH;
        int col = ww * WS + j + 3; if (col >= HH) col -= HH;
        const float* xp = &x[(((size_t)b * HW + row * HH + col) * 96) + part * 24];
        #pragma unroll
        for (int q = 0; q < 6; ++q) xq[q] = *(const float4*)&xp[q * 4];
        float sum = 0.f, sq = 0.f;
        #pragma unroll
        for (int q = 0; q < 6; ++q) {
            sum += xq[q].x + xq[q].y + xq[q].z + xq[q].w;
            sq  += xq[q].x * xq[q].x + xq[q].y * xq[q].y
                 + xq[q].z * xq[q].z + xq[q].w * xq[q].w;
        }
        sum += __shfl_xor(sum, 1); sq += __shfl_xor(sq, 1);
        sum += __shfl_xor(sum, 2); sq += __shfl_xor(sq, 2);
        m = sum * (1.0f / 96.0f);
        rinv = rsqrtf(sq * (1.0f / 96.0f) - m * m + 1e-5f);
    }
    __syncthreads();   // g1/b1 ready; V zeroed

    // ---- normalize in registers -> fp16 A-tiles [12][64][8] ----
    if (active) {
        #pragma unroll
        for (int cc = 0; cc < 3; ++cc) {
            half8 pk;
            #pragma unroll
            for (int j = 0; j < 8; ++j) {
                int c = part * 24 + cc * 8 + j;
                float v; int qi = cc * 2 + (j >> 2);
                if ((j & 3) == 0) v = xq[qi].x;
                else if ((j & 3) == 1) v = xq[qi].y;
                else if ((j & 3) == 2) v = xq[qi].z;
                else v = xq[qi].w;
                pk[j] = (_Float16)((v - m) * rinv * g1[c] + b1[c]);
            }
            *(half8*)&XLN[(part * 3 + cc) * 512 + t_own * 8] = pk;
        }
    }
    __syncthreads();   // XLN ready

    // ---- QKV GEMM: wave wv owns token tile mt=wv ----
    {
        half8 a[3];
        #pragma unroll
        for (int kb = 0; kb < 3; ++kb)
            a[kb] = *(half8*)&XLN[(kb * 4 + l4) * 512 + (wv * 16 + l15) * 8];
        for (int nt = 0; nt < 18; ++nt) {
            f32x4 acc = {0.f, 0.f, 0.f, 0.f};
            #pragma unroll
            for (int kb = 0; kb < 3; ++kb) {
                half8 bw = *(const half8*)&qkvp[((nt * 3 + kb) * 4 + l4) * 128 + l15 * 8];
                acc = MFMA_F16(a[kb], bw, acc, 0, 0, 0);
            }
            int n = nt * 16 + l15;
            float bias = qkv_b[n];
            #pragma unroll
            for (int r = 0; r < 4; ++r) {
                int tok = wv * 16 + l4 * 4 + r;
                if (tok < 49) {
                    _Float16 us = (_Float16)(acc[r] + bias);
                    if (n < 96) {
                        int h = n >> 5, d = n & 31;
                        Qu[(h * 4 + (d >> 3)) * 512 + tok * 8 + (d & 7)] = us;
                    } else if (n < 192) {
                        int m2 = n - 96, h = m2 >> 5, d = m2 & 31;
                        Ku[(h * 4 + (d >> 3)) * 512 + tok * 8 + (d & 7)] = us;
                    } else {
                        int m2 = n - 192, h = m2 >> 5, d = m2 & 31;
                        Vu[(h * 8 + (tok >> 3)) * 256 + d * 8 + (tok & 7)] = us;
                    }
                }
            }
        }
    }
    __syncthreads();   // Q/K/V ready (Q,K pad rows = garbage, provably masked)

    // ---- scores: wave wv owns q-tile; all heads, K=32 single MFMA ----
    f32x4 s[3][4];
    #pragma unroll
    for (int h = 0; h < 3; ++h) {
        half8 qf = *(half8*)&Qu[(h * 4 + l4) * 512 + (wv * 16 + l15) * 8];
        #pragma unroll
        for (int nt = 0; nt < 4; ++nt) {
            half8 kf = *(half8*)&Ku[(h * 4 + l4) * 512 + (nt * 16 + l15) * 8];
            f32x4 z = {0.f, 0.f, 0.f, 0.f};
            s[h][nt] = MFMA_F16(qf, kf, z, 0, 0, 0);
        }
    }
    __syncthreads();   // Q,K dead -> P may overwrite XLN+Qu; Ou may overwrite Ku

    // ---- bias+mask+softmax (registers) -> P fp16 tiles (own stripe only) ----
    {
        const float scale = 0.17677669529663687f;
        int kk[4], lkr[4], lkc[4]; bool kok[4];
        #pragma unroll
        for (int nt = 0; nt < 4; ++nt) {
            int k = nt * 16 + l15;
            kk[nt] = k; kok[nt] = (k < 49);
            int ki = div7d(k), kj = k - ki * 7;
            lkr[nt] = lab4(wh * WS + ki);
            lkc[nt] = lab4(ww * WS + kj);
        }
        #pragma unroll
        for (int h = 0; h < 3; ++h) {
            #pragma unroll
            for (int r = 0; r < 4; ++r) {
                int q = wv * 16 + l4 * 4 + r;
                bool qo = (q < 49);
                int qi = div7d(q), qj = q - qi * 7;
                int lqr = lab4(wh * WS + qi), lqc = lab4(ww * WS + qj);
                float vals[4];
                #pragma unroll
                for (int nt = 0; nt < 4; ++nt) {
                    float v;
                    if (qo && kok[nt]) {
                        v = s[h][nt][r] * scale + attn_bias[(h * 49 + q) * 49 + kk[nt]];
                        if (lqr != lkr[nt] || lqc != lkc[nt]) v -= 100.0f;
                    } else v = -30000.0f;
                    vals[nt] = v;
                }
                float mx = fmaxf(fmaxf(vals[0], vals[1]), fmaxf(vals[2], vals[3]));
                mx = fmaxf(mx, __shfl_xor(mx, 1));
                mx = fmaxf(mx, __shfl_xor(mx, 2));
                mx = fmaxf(mx, __shfl_xor(mx, 4));
                mx = fmaxf(mx, __shfl_xor(mx, 8));
                float e[4], sum = 0.f;
                #pragma unroll
                for (int nt = 0; nt < 4; ++nt) { e[nt] = __expf(vals[nt] - mx); sum += e[nt]; }
                sum += __shfl_xor(sum, 1);
                sum += __shfl_xor(sum, 2);
                sum += __shfl_xor(sum, 4);
                sum += __shfl_xor(sum, 8);
                float inv = 1.0f / sum;
                #pragma unroll
                for (int nt = 0; nt < 4; ++nt)
                    Pu[(h * 8 + (kk[nt] >> 3)) * 512 + q * 8 + (kk[nt] & 7)] = (_Float16)(e[nt] * inv);
            }
        }
    }
    // no barrier: PV reads only this wave's own P stripe

    // ---- PV: O = P @ V (own q-stripe), write fp16 A-tiles over Ku ----
    #pragma unroll
    for (int h = 0; h < 3; ++h) {
        half8 pa0 = *(half8*)&Pu[(h * 8 + 0 + l4) * 512 + (wv * 16 + l15) * 8];
        half8 pa1 = *(half8*)&Pu[(h * 8 + 4 + l4) * 512 + (wv * 16 + l15) * 8];
        #pragma unroll
        for (int ntd = 0; ntd < 2; ++ntd) {
            f32x4 acc = {0.f, 0.f, 0.f, 0.f};
            half8 vb0 = *(half8*)&Vu[(h * 8 + 0 + l4) * 256 + (ntd * 16 + l15) * 8];
            acc = MFMA_F16(pa0, vb0, acc, 0, 0, 0);
            half8 vb1 = *(half8*)&Vu[(h * 8 + 4 + l4) * 256 + (ntd * 16 + l15) * 8];
            acc = MFMA_F16(pa1, vb1, acc, 0, 0, 0);
            int c = h * 32 + ntd * 16 + l15;
            #pragma unroll
            for (int r = 0; r < 4; ++r) {
                int tok = wv * 16 + l4 * 4 + r;
                Ou[(c >> 3) * 512 + tok * 8 + (c & 7)] = (_Float16)acc[r];
            }
        }
    }
    // no barrier: proj reads only this wave's own O stripe

    // ---- proj + residual, direct global scatter ----
    {
        half8 oa[3];
        #pragma unroll
        for (int kb = 0; kb < 3; ++kb)
            oa[kb] = *(half8*)&Ou[(kb * 4 + l4) * 512 + (wv * 16 + l15) * 8];

        size_t tbase[4]; bool tvalid[4];
        #pragma unroll
        for (int r = 0; r < 4; ++r) {
            int tok = wv * 16 + l4 * 4 + r;
            tvalid[r] = (tok < 49);
            int i = div7d(tok & 63), j = (tok & 63) - i * 7;
            int row = wh * WS + i + 3; if (row >= HH) row -= HH;
            int col = ww * WS + j + 3; if (col >= HH) col -= HH;
            tbase[r] = ((size_t)b * HW + row * HH + col) * 96;
        }
        for (int nt = 0; nt < 6; ++nt) {
            f32x4 acc = {0.f, 0.f, 0.f, 0.f};
            #pragma unroll
            for (int kb = 0; kb < 3; ++kb) {
                half8 bw = *(const half8*)&projp[((nt * 3 + kb) * 4 + l4) * 128 + l15 * 8];
                acc = MFMA_F16(oa[kb], bw, acc, 0, 0, 0);
            }
            int n = nt * 16 + l15;
            float pb = proj_b[n];
            #pragma unroll
            for (int r = 0; r < 4; ++r) {
                if (tvalid[r]) {
                    size_t gi = tbase[r] + n;
                    out[gi] = x[gi] + acc[r] + pb;
                }
            }
        }
    }
}

// ---------------------------------------------------------------------------
// MLP: LN2 -> GEMM1(MFMA) -> GELU -> GEMM2(MFMA) + residual, in-place.
// Grid = NTOK/64 = 3136 blocks (ALL tokens).
// ---------------------------------------------------------------------------
__global__ __launch_bounds__(256, 4) void mlp_k4(
    float* __restrict__ xio,
    const float* __restrict__ ln2_g, const float* __restrict__ ln2_b,
    const float* __restrict__ b1v, const float* __restrict__ b2v,
    const _Float16* __restrict__ wpack)
{
    __shared__ _Float16 xln[12 * 520];
    __shared__ _Float16 yb[12 * 520];
    __shared__ float mu[64], rs[64], g[96], bb[96], bi1[96], bi2[96];

    const _Float16* w1p = wpack + W1P_OFF;
    const _Float16* w2p = wpack + W2P_OFF;

    const int tid = threadIdx.x;
    const int wv  = tid >> 6, lane = tid & 63;
    const int l15 = lane & 15, l4 = lane >> 4;
    const size_t tok0 = (size_t)blockIdx.x * 64;

    if (tid < 96) { g[tid] = ln2_g[tid]; bb[tid] = ln2_b[tid]; bi1[tid] = b1v[tid]; bi2[tid] = b2v[tid]; }

    // ---- LN2 stats: 4 threads/token ----
    {
        int t = tid >> 2, part = tid & 3;
        const float* xp = xio + (tok0 + t) * 96 + part * 24;
        float sum = 0.f, sq = 0.f;
        #pragma unroll
        for (int i = 0; i < 6; ++i) {
            float4 v = *(const float4*)&xp[i * 4];
            sum += v.x + v.y + v.z + v.w;
            sq  += v.x * v.x + v.y * v.y + v.z * v.z + v.w * v.w;
        }
        sum += __shfl_xor(sum, 1); sq += __shfl_xor(sq, 1);
        sum += __shfl_xor(sum, 2); sq += __shfl_xor(sq, 2);
        if (part == 0) {
            float m = sum * (1.0f / 96.0f);
            mu[t] = m;
            rs[t] = rsqrtf(sq * (1.0f / 96.0f) - m * m + 1e-5f);
        }
    }
    __syncthreads();

    // ---- normalize -> fp16 A-tiles ----
    for (int idx = tid; idx < 768; idx += 256) {
        int t = idx & 63, chunk = idx >> 6;
        float m = mu[t], r = rs[t];
        const float* xp = &xio[(tok0 + t) * 96 + chunk * 8];
        half8 pk;
        #pragma unroll
        for (int j = 0; j < 8; ++j) {
            int c = chunk * 8 + j;
            pk[j] = (_Float16)((xp[j] - m) * r * g[c] + bb[c]);
        }
        *(half8*)&xln[chunk * 520 + t * 8] = pk;
    }
    __syncthreads();

    // ---- GEMM1 + GELU ----
    {
        half8 a[3];
        #pragma unroll
        for (int kb = 0; kb < 3; ++kb)
            a[kb] = *(half8*)&xln[(kb * 4 + l4) * 520 + (wv * 16 + l15) * 8];
        for (int nt = 0; nt < 6; ++nt) {
            f32x4 acc = {0.f, 0.f, 0.f, 0.f};
            #pragma unroll
            for (int kb = 0; kb < 3; ++kb) {
                half8 bw = *(const half8*)&w1p[((nt * 3 + kb) * 4 + l4) * 128 + l15 * 8];
                acc = MFMA_F16(a[kb], bw, acc, 0, 0, 0);
            }
            int n = nt * 16 + l15;
            float bias = bi1[n];
            #pragma unroll
            for (int r = 0; r < 4; ++r) {
                int tok = wv * 16 + l4 * 4 + r;
                float v = acc[r] + bias;
                v = 0.5f * v * (1.0f + erff(v * 0.70710678118654752f));
                yb[(n >> 3) * 520 + tok * 8 + (n & 7)] = (_Float16)v;
            }
        }
    }
    __syncthreads();

    // ---- GEMM2 + residual ----
    {
        half8 a[3];
        #pragma unroll
        for (int kb = 0; kb < 3; ++kb)
            a[kb] = *(half8*)&yb[(kb * 4 + l4) * 520 + (wv * 16 + l15) * 8];
        for (int nt = 0; nt < 6; ++nt) {
            f32x4 acc = {0.f, 0.f, 0.f, 0.f};
            #pragma unroll
            for (int kb = 0; kb < 3; ++kb) {
                half8 bw = *(const half8*)&w2p[((nt * 3 + kb) * 4 + l4) * 128 + l15 * 8];
                acc = MFMA_F16(a[kb], bw, acc, 0, 0, 0);
            }
            int n = nt * 16 + l15;
            float bias = bi2[n];
            #pragma unroll
            for (int r = 0; r < 4; ++r) {
                int tok = wv * 16 + l4 * 4 + r;
                size_t gi = (tok0 + tok) * 96 + n;
                xio[gi] = xio[gi] + acc[r] + bias;
            }
        }
    }
}

extern "C" void kernel_launch(void* const* d_in, const int* in_sizes, int n_in,
                              void* d_out, int out_size, void* d_ws, size_t ws_size,
                              hipStream_t stream) {
    (void)in_sizes; (void)n_in; (void)ws_size; (void)out_size;
    const float* x         = (const float*)d_in[0];
    const float* qkv_w     = (const float*)d_in[1];
    const float* qkv_b     = (const float*)d_in[2];
    const float* attn_bias = (const float*)d_in[3];
    const float* proj_w    = (const float*)d_in[4];
    const float* proj_b    = (const float*)d_in[5];
    const float* ln1_g     = (const float*)d_in[6];
    const float* ln1_b     = (const float*)d_in[7];
    const float* ln2_g     = (const float*)d_in[8];
    const float* ln2_b     = (const float*)d_in[9];
    const float* mlp_w1    = (const float*)d_in[10];
    const float* mlp_b1    = (const float*)d_in[11];
    const float* mlp_w2    = (const float*)d_in[12];
    const float* mlp_b2    = (const float*)d_in[13];
    float* out = (float*)d_out;
    _Float16* wpack = (_Float16*)d_ws;

    pack_w4<<<216, 256, 0, stream>>>(qkv_w, proj_w, mlp_w1, mlp_w2, wpack);
    attn_k4<<<64 * 64, 256, 0, stream>>>(x, qkv_b, attn_bias, proj_b,
                                         ln1_g, ln1_b, wpack, out);
    mlp_k4<<<NTOK / 64, 256, 0, stream>>>(out, ln2_g, ln2_b, mlp_b1, mlp_b2, wpack);
}

// Round 8
// 191.296 us; speedup vs baseline: 5.1286x; 1.1837x over previous
//
#include <hip/hip_runtime.h>
#include <math.h>

typedef _Float16 half8 __attribute__((ext_vector_type(8)));
typedef float f32x4 __attribute__((ext_vector_type(4)));

#define MFMA_F16 __builtin_amdgcn_mfma_f32_16x16x32_f16

constexpr int WS = 7, HH = 56, HW = 3136;
constexpr int NTOK = 64 * HW;      // 200704 total tokens

// d_ws layout (fp16 element offsets)
constexpr int QKVP_OFF  = 0;       // 27648
constexpr int PROJP_OFF = 27648;   // 9216
constexpr int W1P_OFF   = 36864;   // 9216
constexpr int W2P_OFF   = 46080;   // 9216

__device__ __forceinline__ int lab5(int v) { return v < 49 ? 0 : (v < 53 ? 1 : 2); }
__device__ __forceinline__ int div7e(int v) { return (v * 9363) >> 16; }  // valid 0..63

// ---------------------------------------------------------------------------
// Weight pre-pack: f32 [K][N] row-major -> fp16 B-fragment tiles
// ---------------------------------------------------------------------------
__global__ __launch_bounds__(256) void pack_w5(
    const float* __restrict__ qkv_w, const float* __restrict__ proj_w,
    const float* __restrict__ w1, const float* __restrict__ w2,
    _Float16* __restrict__ ws)
{
    int i = blockIdx.x * 256 + threadIdx.x;
    const float* src; int ncol, local;
    if (i < 27648)      { src = qkv_w;  ncol = 288; local = i; }
    else if (i < 36864) { src = proj_w; ncol = 96;  local = i - 27648; }
    else if (i < 46080) { src = w1;     ncol = 96;  local = i - 36864; }
    else                { src = w2;     ncol = 96;  local = i - 46080; }
    int j = local & 7, col = (local >> 3) & 15, ksub = (local >> 7) & 3;
    int rest = local >> 9;
    int kb = rest % 3, nt = rest / 3;
    int k = kb * 32 + ksub * 8 + j, n = nt * 16 + col;
    ws[i] = (_Float16)src[k * ncol + n];
}

// ---------------------------------------------------------------------------
// attn: reg-gather+LN1 -> QKV (MFMA) -> scores (MFMA) -> reg softmax ->
//       PV (MFMA) -> proj (MFMA) -> direct global scatter(+residual).
// One block per (batch, window). 4 barriers. 36.8 KB LDS -> 4 blocks/CU.
// LDS byte map (aliases; all alias hazards are wave-private own-stripe rows
// or guarded by the existing barriers):
//   [0,12288)      XLN fp16 [12][64][8]  -> Qu fp16 [3][4][64][8] (stripe-
//                  private swap)         -> Pu lower 12 planes -> Ou (in-place
//                  over own P stripe rows)
//   [12288,24576)  Ku  fp16 [3][4][64][8] -> Pu upper 12 planes
//   [24576,36864)  Vu  fp16 [3][8][32][8]
// ---------------------------------------------------------------------------
__global__ __launch_bounds__(256, 4) void attn_k5(
    const float* __restrict__ x,
    const float* __restrict__ qkv_b,
    const float* __restrict__ attn_bias,
    const float* __restrict__ proj_b,
    const float* __restrict__ ln1_g,
    const float* __restrict__ ln1_b,
    const _Float16* __restrict__ wpack,
    float* __restrict__ out)
{
    __shared__ __align__(16) char smem[36864];
    __shared__ float g1[96], b1[96];

    _Float16*  XLN = (_Float16*)smem;
    _Float16*  Qu  = (_Float16*)smem;            // over XLN (stripe-private)
    _Float16*  Ku  = (_Float16*)(smem + 12288);
    _Float16*  Vu  = (_Float16*)(smem + 24576);
    _Float16*  Pu  = (_Float16*)smem;            // 24576 B spanning Qu+Ku
    _Float16*  Ou  = (_Float16*)smem;            // planes 0..11, own rows

    const _Float16* qkvp  = wpack + QKVP_OFF;
    const _Float16* projp = wpack + PROJP_OFF;

    const int blk = blockIdx.x;
    const int b   = blk >> 6;
    const int w   = blk & 63;
    const int wh  = w >> 3, ww = w & 7;
    const int tid = threadIdx.x;
    const int wv  = tid >> 6, lane = tid & 63;
    const int l15 = lane & 15, l4 = lane >> 4;

    if (tid < 96) { g1[tid] = ln1_g[tid]; b1[tid] = ln1_b[tid]; }

    // ---- zero V pad region (768 * 16B = 12288B) ----
    for (int idx = tid; idx < 768; idx += 256)
        ((uint4*)Vu)[idx] = make_uint4(0, 0, 0, 0);

    // ---- gather window (rolled) into registers: 4 threads/token x 24 ch ----
    const int t_own = tid >> 2, part = tid & 3;
    const bool active = (tid < 196);
    float4 xq[6];
    float m = 0.f, rinv = 0.f;
    if (active) {
        int i = div7e(t_own), j = t_own - i * 7;
        int row = wh * WS + i + 3; if (row >= HH) row -= HH;
        int col = ww * WS + j + 3; if (col >= HH) col -= HH;
        const float* xp = &x[(((size_t)b * HW + row * HH + col) * 96) + part * 24];
        #pragma unroll
        for (int q = 0; q < 6; ++q) xq[q] = *(const float4*)&xp[q * 4];
        float sum = 0.f, sq = 0.f;
        #pragma unroll
        for (int q = 0; q < 6; ++q) {
            sum += xq[q].x + xq[q].y + xq[q].z + xq[q].w;
            sq  += xq[q].x * xq[q].x + xq[q].y * xq[q].y
                 + xq[q].z * xq[q].z + xq[q].w * xq[q].w;
        }
        sum += __shfl_xor(sum, 1); sq += __shfl_xor(sq, 1);
        sum += __shfl_xor(sum, 2); sq += __shfl_xor(sq, 2);
        m = sum * (1.0f / 96.0f);
        rinv = rsqrtf(sq * (1.0f / 96.0f) - m * m + 1e-5f);
    }
    __syncthreads();   // g1/b1 ready; V zeroed

    // ---- normalize in registers -> fp16 A-tiles [12][64][8] (own stripe) ----
    if (active) {
        #pragma unroll
        for (int cc = 0; cc < 3; ++cc) {
            half8 pk;
            #pragma unroll
            for (int j = 0; j < 8; ++j) {
                int c = part * 24 + cc * 8 + j;
                float v; int qi = cc * 2 + (j >> 2);
                if ((j & 3) == 0) v = xq[qi].x;
                else if ((j & 3) == 1) v = xq[qi].y;
                else if ((j & 3) == 2) v = xq[qi].z;
                else v = xq[qi].w;
                pk[j] = (_Float16)((v - m) * rinv * g1[c] + b1[c]);
            }
            *(half8*)&XLN[(part * 3 + cc) * 512 + t_own * 8] = pk;
        }
    }
    __syncthreads();   // XLN ready

    // ---- QKV GEMM: wave wv owns token tile mt=wv ----
    {
        half8 a[3];
        #pragma unroll
        for (int kb = 0; kb < 3; ++kb)
            a[kb] = *(half8*)&XLN[(kb * 4 + l4) * 512 + (wv * 16 + l15) * 8];
        // XLN own-stripe rows now in regs; Q writes below reuse the region
        // (stripe-private across waves, in-order within wave).
        for (int nt = 0; nt < 18; ++nt) {
            f32x4 acc = {0.f, 0.f, 0.f, 0.f};
            #pragma unroll
            for (int kb = 0; kb < 3; ++kb) {
                half8 bw = *(const half8*)&qkvp[((nt * 3 + kb) * 4 + l4) * 128 + l15 * 8];
                acc = MFMA_F16(a[kb], bw, acc, 0, 0, 0);
            }
            int n = nt * 16 + l15;
            float bias = qkv_b[n];
            #pragma unroll
            for (int r = 0; r < 4; ++r) {
                int tok = wv * 16 + l4 * 4 + r;
                if (tok < 49) {
                    _Float16 us = (_Float16)(acc[r] + bias);
                    if (n < 96) {
                        int h = n >> 5, d = n & 31;
                        Qu[(h * 4 + (d >> 3)) * 512 + tok * 8 + (d & 7)] = us;
                    } else if (n < 192) {
                        int m2 = n - 96, h = m2 >> 5, d = m2 & 31;
                        Ku[(h * 4 + (d >> 3)) * 512 + tok * 8 + (d & 7)] = us;
                    } else {
                        int m2 = n - 192, h = m2 >> 5, d = m2 & 31;
                        Vu[(h * 8 + (tok >> 3)) * 256 + d * 8 + (tok & 7)] = us;
                    }
                }
            }
        }
    }
    __syncthreads();   // Q/K/V ready (pad rows garbage, provably masked)

    // ---- scores: wave wv owns q-tile; all heads, K=32 single MFMA ----
    f32x4 s[3][4];
    #pragma unroll
    for (int h = 0; h < 3; ++h) {
        half8 qf = *(half8*)&Qu[(h * 4 + l4) * 512 + (wv * 16 + l15) * 8];
        #pragma unroll
        for (int nt = 0; nt < 4; ++nt) {
            half8 kf = *(half8*)&Ku[(h * 4 + l4) * 512 + (nt * 16 + l15) * 8];
            f32x4 z = {0.f, 0.f, 0.f, 0.f};
            s[h][nt] = MFMA_F16(qf, kf, z, 0, 0, 0);
        }
    }
    __syncthreads();   // Q,K dead for ALL waves -> P may overwrite Qu+Ku

    // ---- bias+mask+softmax (registers) -> P fp16 tiles (own stripe only) ----
    {
        const float scale = 0.17677669529663687f;
        int kk[4], lkr[4], lkc[4]; bool kok[4];
        #pragma unroll
        for (int nt = 0; nt < 4; ++nt) {
            int k = nt * 16 + l15;
            kk[nt] = k; kok[nt] = (k < 49);
            int ki = div7e(k), kj = k - ki * 7;
            lkr[nt] = lab5(wh * WS + ki);
            lkc[nt] = lab5(ww * WS + kj);
        }
        #pragma unroll
        for (int h = 0; h < 3; ++h) {
            #pragma unroll
            for (int r = 0; r < 4; ++r) {
                int q = wv * 16 + l4 * 4 + r;
                bool qo = (q < 49);
                int qi = div7e(q), qj = q - qi * 7;
                int lqr = lab5(wh * WS + qi), lqc = lab5(ww * WS + qj);
                float vals[4];
                #pragma unroll
                for (int nt = 0; nt < 4; ++nt) {
                    float v;
                    if (qo && kok[nt]) {
                        v = s[h][nt][r] * scale + attn_bias[(h * 49 + q) * 49 + kk[nt]];
                        if (lqr != lkr[nt] || lqc != lkc[nt]) v -= 100.0f;
                    } else v = -30000.0f;
                    vals[nt] = v;
                }
                float mx = fmaxf(fmaxf(vals[0], vals[1]), fmaxf(vals[2], vals[3]));
                mx = fmaxf(mx, __shfl_xor(mx, 1));
                mx = fmaxf(mx, __shfl_xor(mx, 2));
                mx = fmaxf(mx, __shfl_xor(mx, 4));
                mx = fmaxf(mx, __shfl_xor(mx, 8));
                float e[4], sum = 0.f;
                #pragma unroll
                for (int nt = 0; nt < 4; ++nt) { e[nt] = __expf(vals[nt] - mx); sum += e[nt]; }
                sum += __shfl_xor(sum, 1);
                sum += __shfl_xor(sum, 2);
                sum += __shfl_xor(sum, 4);
                sum += __shfl_xor(sum, 8);
                float inv = 1.0f / sum;
                #pragma unroll
                for (int nt = 0; nt < 4; ++nt)
                    Pu[(h * 8 + (kk[nt] >> 3)) * 512 + q * 8 + (kk[nt] & 7)] = (_Float16)(e[nt] * inv);
            }
        }
    }
    // no barrier: everything below is wave-private (own-stripe rows) or
    // read-only V.

    // ---- PV: O = P @ V (own q-stripe); O overwrites own P rows in place ----
    #pragma unroll
    for (int h = 0; h < 3; ++h) {
        half8 pa0 = *(half8*)&Pu[(h * 8 + 0 + l4) * 512 + (wv * 16 + l15) * 8];
        half8 pa1 = *(half8*)&Pu[(h * 8 + 4 + l4) * 512 + (wv * 16 + l15) * 8];
        #pragma unroll
        for (int ntd = 0; ntd < 2; ++ntd) {
            f32x4 acc = {0.f, 0.f, 0.f, 0.f};
            half8 vb0 = *(half8*)&Vu[(h * 8 + 0 + l4) * 256 + (ntd * 16 + l15) * 8];
            acc = MFMA_F16(pa0, vb0, acc, 0, 0, 0);
            half8 vb1 = *(half8*)&Vu[(h * 8 + 4 + l4) * 256 + (ntd * 16 + l15) * 8];
            acc = MFMA_F16(pa1, vb1, acc, 0, 0, 0);
            int c = h * 32 + ntd * 16 + l15;
            #pragma unroll
            for (int r = 0; r < 4; ++r) {
                int tok = wv * 16 + l4 * 4 + r;
                Ou[(c >> 3) * 512 + tok * 8 + (c & 7)] = (_Float16)acc[r];
            }
        }
    }
    // no barrier: proj reads only this wave's own O stripe rows

    // ---- proj + residual, direct global scatter ----
    {
        half8 oa[3];
        #pragma unroll
        for (int kb = 0; kb < 3; ++kb)
            oa[kb] = *(half8*)&Ou[(kb * 4 + l4) * 512 + (wv * 16 + l15) * 8];

        size_t tbase[4]; bool tvalid[4];
        #pragma unroll
        for (int r = 0; r < 4; ++r) {
            int tok = wv * 16 + l4 * 4 + r;
            tvalid[r] = (tok < 49);
            int i = div7e(tok & 63), j = (tok & 63) - i * 7;
            int row = wh * WS + i + 3; if (row >= HH) row -= HH;
            int col = ww * WS + j + 3; if (col >= HH) col -= HH;
            tbase[r] = ((size_t)b * HW + row * HH + col) * 96;
        }
        for (int nt = 0; nt < 6; ++nt) {
            f32x4 acc = {0.f, 0.f, 0.f, 0.f};
            #pragma unroll
            for (int kb = 0; kb < 3; ++kb) {
                half8 bw = *(const half8*)&projp[((nt * 3 + kb) * 4 + l4) * 128 + l15 * 8];
                acc = MFMA_F16(oa[kb], bw, acc, 0, 0, 0);
            }
            int n = nt * 16 + l15;
            float pb = proj_b[n];
            #pragma unroll
            for (int r = 0; r < 4; ++r) {
                if (tvalid[r]) {
                    size_t gi = tbase[r] + n;
                    out[gi] = x[gi] + acc[r] + pb;
                }
            }
        }
    }
}

// ---------------------------------------------------------------------------
// MLP: LN2 -> GEMM1(MFMA) -> GELU -> GEMM2(MFMA) + residual, in-place.
// Grid = NTOK/64 = 3136 blocks (ALL tokens).
// ---------------------------------------------------------------------------
__global__ __launch_bounds__(256, 4) void mlp_k5(
    float* __restrict__ xio,
    const float* __restrict__ ln2_g, const float* __restrict__ ln2_b,
    const float* __restrict__ b1v, const float* __restrict__ b2v,
    const _Float16* __restrict__ wpack)
{
    __shared__ _Float16 xln[12 * 520];
    __shared__ _Float16 yb[12 * 520];
    __shared__ float mu[64], rs[64], g[96], bb[96], bi1[96], bi2[96];

    const _Float16* w1p = wpack + W1P_OFF;
    const _Float16* w2p = wpack + W2P_OFF;

    const int tid = threadIdx.x;
    const int wv  = tid >> 6, lane = tid & 63;
    const int l15 = lane & 15, l4 = lane >> 4;
    const size_t tok0 = (size_t)blockIdx.x * 64;

    if (tid < 96) { g[tid] = ln2_g[tid]; bb[tid] = ln2_b[tid]; bi1[tid] = b1v[tid]; bi2[tid] = b2v[tid]; }

    // ---- LN2 stats: 4 threads/token ----
    {
        int t = tid >> 2, part = tid & 3;
        const float* xp = xio + (tok0 + t) * 96 + part * 24;
        float sum = 0.f, sq = 0.f;
        #pragma unroll
        for (int i = 0; i < 6; ++i) {
            float4 v = *(const float4*)&xp[i * 4];
            sum += v.x + v.y + v.z + v.w;
            sq  += v.x * v.x + v.y * v.y + v.z * v.z + v.w * v.w;
        }
        sum += __shfl_xor(sum, 1); sq += __shfl_xor(sq, 1);
        sum += __shfl_xor(sum, 2); sq += __shfl_xor(sq, 2);
        if (part == 0) {
            float m = sum * (1.0f / 96.0f);
            mu[t] = m;
            rs[t] = rsqrtf(sq * (1.0f / 96.0f) - m * m + 1e-5f);
        }
    }
    __syncthreads();

    // ---- normalize -> fp16 A-tiles ----
    for (int idx = tid; idx < 768; idx += 256) {
        int t = idx & 63, chunk = idx >> 6;
        float m = mu[t], r = rs[t];
        const float* xp = &xio[(tok0 + t) * 96 + chunk * 8];
        half8 pk;
        #pragma unroll
        for (int j = 0; j < 8; ++j) {
            int c = chunk * 8 + j;
            pk[j] = (_Float16)((xp[j] - m) * r * g[c] + bb[c]);
        }
        *(half8*)&xln[chunk * 520 + t * 8] = pk;
    }
    __syncthreads();

    // ---- GEMM1 + GELU ----
    {
        half8 a[3];
        #pragma unroll
        for (int kb = 0; kb < 3; ++kb)
            a[kb] = *(half8*)&xln[(kb * 4 + l4) * 520 + (wv * 16 + l15) * 8];
        for (int nt = 0; nt < 6; ++nt) {
            f32x4 acc = {0.f, 0.f, 0.f, 0.f};
            #pragma unroll
            for (int kb = 0; kb < 3; ++kb) {
                half8 bw = *(const half8*)&w1p[((nt * 3 + kb) * 4 + l4) * 128 + l15 * 8];
                acc = MFMA_F16(a[kb], bw, acc, 0, 0, 0);
            }
            int n = nt * 16 + l15;
            float bias = bi1[n];
            #pragma unroll
            for (int r = 0; r < 4; ++r) {
                int tok = wv * 16 + l4 * 4 + r;
                float v = acc[r] + bias;
                v = 0.5f * v * (1.0f + erff(v * 0.70710678118654752f));
                yb[(n >> 3) * 520 + tok * 8 + (n & 7)] = (_Float16)v;
            }
        }
    }
    __syncthreads();

    // ---- GEMM2 + residual ----
    {
        half8 a[3];
        #pragma unroll
        for (int kb = 0; kb < 3; ++kb)
            a[kb] = *(half8*)&yb[(kb * 4 + l4) * 520 + (wv * 16 + l15) * 8];
        for (int nt = 0; nt < 6; ++nt) {
            f32x4 acc = {0.f, 0.f, 0.f, 0.f};
            #pragma unroll
            for (int kb = 0; kb < 3; ++kb) {
                half8 bw = *(const half8*)&w2p[((nt * 3 + kb) * 4 + l4) * 128 + l15 * 8];
                acc = MFMA_F16(a[kb], bw, acc, 0, 0, 0);
            }
            int n = nt * 16 + l15;
            float bias = bi2[n];
            #pragma unroll
            for (int r = 0; r < 4; ++r) {
                int tok = wv * 16 + l4 * 4 + r;
                size_t gi = (tok0 + tok) * 96 + n;
                xio[gi] = xio[gi] + acc[r] + bias;
            }
        }
    }
}

extern "C" void kernel_launch(void* const* d_in, const int* in_sizes, int n_in,
                              void* d_out, int out_size, void* d_ws, size_t ws_size,
                              hipStream_t stream) {
    (void)in_sizes; (void)n_in; (void)ws_size; (void)out_size;
    const float* x         = (const float*)d_in[0];
    const float* qkv_w     = (const float*)d_in[1];
    const float* qkv_b     = (const float*)d_in[2];
    const float* attn_bias = (const float*)d_in[3];
    const float* proj_w    = (const float*)d_in[4];
    const float* proj_b    = (const float*)d_in[5];
    const float* ln1_g     = (const float*)d_in[6];
    const float* ln1_b     = (const float*)d_in[7];
    const float* ln2_g     = (const float*)d_in[8];
    const float* ln2_b     = (const float*)d_in[9];
    const float* mlp_w1    = (const float*)d_in[10];
    const float* mlp_b1    = (const float*)d_in[11];
    const float* mlp_w2    = (const float*)d_in[12];
    const float* mlp_b2    = (const float*)d_in[13];
    float* out = (float*)d_out;
    _Float16* wpack = (_Float16*)d_ws;

    pack_w5<<<216, 256, 0, stream>>>(qkv_w, proj_w, mlp_w1, mlp_w2, wpack);
    attn_k5<<<64 * 64, 256, 0, stream>>>(x, qkv_b, attn_bias, proj_b,
                                         ln1_g, ln1_b, wpack, out);
    mlp_k5<<<NTOK / 64, 256, 0, stream>>>(out, ln2_g, ln2_b, mlp_b1, mlp_b2, wpack);
}

// Round 9
// 160.209 us; speedup vs baseline: 6.1237x; 1.1940x over previous
//
#include <hip/hip_runtime.h>
#include <math.h>

typedef _Float16 half8 __attribute__((ext_vector_type(8)));
typedef float f32x4 __attribute__((ext_vector_type(4)));

#define MFMA_F16 __builtin_amdgcn_mfma_f32_16x16x32_f16

constexpr int WS = 7, HH = 56, HW = 3136;

// d_ws layout (fp16 element offsets)
constexpr int QKVP_OFF  = 0;       // 27648
constexpr int PROJP_OFF = 27648;   // 9216
constexpr int W1P_OFF   = 36864;   // 9216
constexpr int W2P_OFF   = 46080;   // 9216

__device__ __forceinline__ int lab6(int v) { return v < 49 ? 0 : (v < 53 ? 1 : 2); }
__device__ __forceinline__ int div7f(int v) { return (v * 9363) >> 16; }  // valid 0..63

// ---------------------------------------------------------------------------
// Weight pre-pack: f32 [K][N] row-major -> fp16 B-fragment tiles
// ---------------------------------------------------------------------------
__global__ __launch_bounds__(256) void pack_w6(
    const float* __restrict__ qkv_w, const float* __restrict__ proj_w,
    const float* __restrict__ w1, const float* __restrict__ w2,
    _Float16* __restrict__ ws)
{
    int i = blockIdx.x * 256 + threadIdx.x;
    const float* src; int ncol, local;
    if (i < 27648)      { src = qkv_w;  ncol = 288; local = i; }
    else if (i < 36864) { src = proj_w; ncol = 96;  local = i - 27648; }
    else if (i < 46080) { src = w1;     ncol = 96;  local = i - 36864; }
    else                { src = w2;     ncol = 96;  local = i - 46080; }
    int j = local & 7, col = (local >> 3) & 15, ksub = (local >> 7) & 3;
    int rest = local >> 9;
    int kb = rest % 3, nt = rest / 3;
    int k = kb * 32 + ksub * 8 + j, n = nt * 16 + col;
    ws[i] = (_Float16)src[k * ncol + n];
}

// ---------------------------------------------------------------------------
// Fully fused Swin block: gather+LN1 -> QKV -> scores -> softmax -> PV ->
// proj(+residual, regs) -> LN2 -> MLP GEMM1+GELU -> GEMM2 -> out.
// One block per (batch, window); 3 barriers; 39.2 KB LDS -> 4 blocks/CU.
// LDS region (36864 B), aliased over time:
//   planes 0-11  [0,12288):   XLN -> Qu -> Pu(lo) -> Ou -> x~(MLP A-tiles)
//   planes 12-23 [12288,24576): Ku -> Pu(hi) -> yb(MLP mid tiles)
//   planes 24-35 [24576,36864): Vu
// All no-barrier aliases are own-wave, own-stripe rows (in-order DS pipe).
// ---------------------------------------------------------------------------
__global__ __launch_bounds__(256, 4) void attn_k6(
    const float* __restrict__ x,
    const float* __restrict__ qkv_b,
    const float* __restrict__ attn_bias,
    const float* __restrict__ proj_b,
    const float* __restrict__ ln1_g,
    const float* __restrict__ ln1_b,
    const float* __restrict__ ln2_g,
    const float* __restrict__ ln2_b,
    const float* __restrict__ mlp_b1,
    const float* __restrict__ mlp_b2,
    const _Float16* __restrict__ wpack,
    float* __restrict__ out)
{
    __shared__ __align__(16) char smem[36864];
    __shared__ float g1[96], b1[96], g2[96], bb2[96], bi1[96], bi2[96];

    _Float16*  XLN = (_Float16*)smem;
    _Float16*  Qu  = (_Float16*)smem;
    _Float16*  Ku  = (_Float16*)(smem + 12288);
    _Float16*  Vu  = (_Float16*)(smem + 24576);
    _Float16*  Pu  = (_Float16*)smem;            // 24 planes spanning Qu+Ku
    _Float16*  Ou  = (_Float16*)smem;            // planes 0..11, own rows
    _Float16*  XT  = (_Float16*)smem;            // MLP x~ tiles, planes 0..11
    _Float16*  YT  = (_Float16*)(smem + 12288);  // MLP mid tiles, planes 12..23

    const _Float16* qkvp  = wpack + QKVP_OFF;
    const _Float16* projp = wpack + PROJP_OFF;
    const _Float16* w1p   = wpack + W1P_OFF;
    const _Float16* w2p   = wpack + W2P_OFF;

    const int blk = blockIdx.x;
    const int b   = blk >> 6;
    const int w   = blk & 63;
    const int wh  = w >> 3, ww = w & 7;
    const int tid = threadIdx.x;
    const int wv  = tid >> 6, lane = tid & 63;
    const int l15 = lane & 15, l4 = lane >> 4;

    if (tid < 96) {
        g1[tid] = ln1_g[tid]; b1[tid] = ln1_b[tid];
        g2[tid] = ln2_g[tid]; bb2[tid] = ln2_b[tid];
        bi1[tid] = mlp_b1[tid]; bi2[tid] = mlp_b2[tid];
    }

    // ---- zero V pad region ----
    for (int idx = tid; idx < 768; idx += 256)
        ((uint4*)Vu)[idx] = make_uint4(0, 0, 0, 0);

    // ---- gather window (rolled) into registers: 4 threads/token x 24 ch ----
    const int t_own = tid >> 2, part = tid & 3;
    const bool active = (tid < 196);
    float4 xq[6];
    float m = 0.f, rinv = 0.f;
    if (active) {
        int i = div7f(t_own), j = t_own - i * 7;
        int row = wh * WS + i + 3; if (row >= HH) row -= HH;
        int col = ww * WS + j + 3; if (col >= HH) col -= HH;
        const float* xp = &x[(((size_t)b * HW + row * HH + col) * 96) + part * 24];
        #pragma unroll
        for (int q = 0; q < 6; ++q) xq[q] = *(const float4*)&xp[q * 4];
        float sum = 0.f, sq = 0.f;
        #pragma unroll
        for (int q = 0; q < 6; ++q) {
            sum += xq[q].x + xq[q].y + xq[q].z + xq[q].w;
            sq  += xq[q].x * xq[q].x + xq[q].y * xq[q].y
                 + xq[q].z * xq[q].z + xq[q].w * xq[q].w;
        }
        sum += __shfl_xor(sum, 1); sq += __shfl_xor(sq, 1);
        sum += __shfl_xor(sum, 2); sq += __shfl_xor(sq, 2);
        m = sum * (1.0f / 96.0f);
        rinv = rsqrtf(sq * (1.0f / 96.0f) - m * m + 1e-5f);
    }
    __syncthreads();   // B1: consts ready; V zeroed

    // ---- normalize -> XLN A-tiles (rows are own-wave: thread 4t in wave t>>4)
    if (active) {
        #pragma unroll
        for (int cc = 0; cc < 3; ++cc) {
            half8 pk;
            #pragma unroll
            for (int j = 0; j < 8; ++j) {
                int c = part * 24 + cc * 8 + j;
                float v; int qi = cc * 2 + (j >> 2);
                if ((j & 3) == 0) v = xq[qi].x;
                else if ((j & 3) == 1) v = xq[qi].y;
                else if ((j & 3) == 2) v = xq[qi].z;
                else v = xq[qi].w;
                pk[j] = (_Float16)((v - m) * rinv * g1[c] + b1[c]);
            }
            *(half8*)&XLN[(part * 3 + cc) * 512 + t_own * 8] = pk;
        }
    }
    // NO barrier: QKV A-frags read own-stripe rows written by this wave.

    // ---- QKV GEMM: wave wv owns token tile mt=wv ----
    {
        half8 a[3];
        #pragma unroll
        for (int kb = 0; kb < 3; ++kb)
            a[kb] = *(half8*)&XLN[(kb * 4 + l4) * 512 + (wv * 16 + l15) * 8];
        for (int nt = 0; nt < 18; ++nt) {
            f32x4 acc = {0.f, 0.f, 0.f, 0.f};
            #pragma unroll
            for (int kb = 0; kb < 3; ++kb) {
                half8 bw = *(const half8*)&qkvp[((nt * 3 + kb) * 4 + l4) * 128 + l15 * 8];
                acc = MFMA_F16(a[kb], bw, acc, 0, 0, 0);
            }
            int n = nt * 16 + l15;
            float bias = qkv_b[n];
            #pragma unroll
            for (int r = 0; r < 4; ++r) {
                int tok = wv * 16 + l4 * 4 + r;
                if (tok < 49) {
                    _Float16 us = (_Float16)(acc[r] + bias);
                    if (n < 96) {
                        int h = n >> 5, d = n & 31;
                        Qu[(h * 4 + (d >> 3)) * 512 + tok * 8 + (d & 7)] = us;
                    } else if (n < 192) {
                        int m2 = n - 96, h = m2 >> 5, d = m2 & 31;
                        Ku[(h * 4 + (d >> 3)) * 512 + tok * 8 + (d & 7)] = us;
                    } else {
                        int m2 = n - 192, h = m2 >> 5, d = m2 & 31;
                        Vu[(h * 8 + (tok >> 3)) * 256 + d * 8 + (tok & 7)] = us;
                    }
                }
            }
        }
    }
    __syncthreads();   // B2: K/V cross-wave reads below (pad rows masked)

    // ---- scores: wave wv owns q-tile; all heads, K=32 single MFMA ----
    f32x4 s[3][4];
    #pragma unroll
    for (int h = 0; h < 3; ++h) {
        half8 qf = *(half8*)&Qu[(h * 4 + l4) * 512 + (wv * 16 + l15) * 8];
        #pragma unroll
        for (int nt = 0; nt < 4; ++nt) {
            half8 kf = *(half8*)&Ku[(h * 4 + l4) * 512 + (nt * 16 + l15) * 8];
            f32x4 z = {0.f, 0.f, 0.f, 0.f};
            s[h][nt] = MFMA_F16(qf, kf, z, 0, 0, 0);
        }
    }
    __syncthreads();   // B3: Q,K dead for ALL waves -> P may overwrite

    // ---- bias+mask+softmax (registers) -> P tiles (own stripe rows) ----
    {
        const float scale = 0.17677669529663687f;
        int kk[4], lkr[4], lkc[4]; bool kok[4];
        #pragma unroll
        for (int nt = 0; nt < 4; ++nt) {
            int k = nt * 16 + l15;
            kk[nt] = k; kok[nt] = (k < 49);
            int ki = div7f(k), kj = k - ki * 7;
            lkr[nt] = lab6(wh * WS + ki);
            lkc[nt] = lab6(ww * WS + kj);
        }
        #pragma unroll
        for (int h = 0; h < 3; ++h) {
            #pragma unroll
            for (int r = 0; r < 4; ++r) {
                int q = wv * 16 + l4 * 4 + r;
                bool qo = (q < 49);
                int qi = div7f(q), qj = q - qi * 7;
                int lqr = lab6(wh * WS + qi), lqc = lab6(ww * WS + qj);
                float vals[4];
                #pragma unroll
                for (int nt = 0; nt < 4; ++nt) {
                    float v;
                    if (qo && kok[nt]) {
                        v = s[h][nt][r] * scale + attn_bias[(h * 49 + q) * 49 + kk[nt]];
                        if (lqr != lkr[nt] || lqc != lkc[nt]) v -= 100.0f;
                    } else v = -30000.0f;
                    vals[nt] = v;
                }
                float mx = fmaxf(fmaxf(vals[0], vals[1]), fmaxf(vals[2], vals[3]));
                mx = fmaxf(mx, __shfl_xor(mx, 1));
                mx = fmaxf(mx, __shfl_xor(mx, 2));
                mx = fmaxf(mx, __shfl_xor(mx, 4));
                mx = fmaxf(mx, __shfl_xor(mx, 8));
                float e[4], sum = 0.f;
                #pragma unroll
                for (int nt = 0; nt < 4; ++nt) { e[nt] = __expf(vals[nt] - mx); sum += e[nt]; }
                sum += __shfl_xor(sum, 1);
                sum += __shfl_xor(sum, 2);
                sum += __shfl_xor(sum, 4);
                sum += __shfl_xor(sum, 8);
                float inv = 1.0f / sum;
                #pragma unroll
                for (int nt = 0; nt < 4; ++nt)
                    Pu[(h * 8 + (kk[nt] >> 3)) * 512 + q * 8 + (kk[nt] & 7)] = (_Float16)(e[nt] * inv);
            }
        }
    }
    // Everything below is wave-private (own-stripe rows) or read-only V:
    // no more barriers.

    // ---- PV: O = P @ V (own q-stripe); O over own P rows ----
    #pragma unroll
    for (int h = 0; h < 3; ++h) {
        half8 pa0 = *(half8*)&Pu[(h * 8 + 0 + l4) * 512 + (wv * 16 + l15) * 8];
        half8 pa1 = *(half8*)&Pu[(h * 8 + 4 + l4) * 512 + (wv * 16 + l15) * 8];
        #pragma unroll
        for (int ntd = 0; ntd < 2; ++ntd) {
            f32x4 acc = {0.f, 0.f, 0.f, 0.f};
            half8 vb0 = *(half8*)&Vu[(h * 8 + 0 + l4) * 256 + (ntd * 16 + l15) * 8];
            acc = MFMA_F16(pa0, vb0, acc, 0, 0, 0);
            half8 vb1 = *(half8*)&Vu[(h * 8 + 4 + l4) * 256 + (ntd * 16 + l15) * 8];
            acc = MFMA_F16(pa1, vb1, acc, 0, 0, 0);
            int c = h * 32 + ntd * 16 + l15;
            #pragma unroll
            for (int r = 0; r < 4; ++r) {
                int tok = wv * 16 + l4 * 4 + r;
                Ou[(c >> 3) * 512 + tok * 8 + (c & 7)] = (_Float16)acc[r];
            }
        }
    }

    // ---- proj + residual into REGISTERS (x2 = x + attn_out) ----
    float x2v[6][4];
    size_t tbase[4]; bool tvalid[4];
    {
        half8 oa[3];
        #pragma unroll
        for (int kb = 0; kb < 3; ++kb)
            oa[kb] = *(half8*)&Ou[(kb * 4 + l4) * 512 + (wv * 16 + l15) * 8];

        #pragma unroll
        for (int r = 0; r < 4; ++r) {
            int tok = wv * 16 + l4 * 4 + r;
            tvalid[r] = (tok < 49);
            int i = div7f(tok & 63), j = (tok & 63) - i * 7;
            int row = wh * WS + i + 3; if (row >= HH) row -= HH;
            int col = ww * WS + j + 3; if (col >= HH) col -= HH;
            tbase[r] = ((size_t)b * HW + row * HH + col) * 96;
        }
        for (int nt = 0; nt < 6; ++nt) {
            f32x4 acc = {0.f, 0.f, 0.f, 0.f};
            #pragma unroll
            for (int kb = 0; kb < 3; ++kb) {
                half8 bw = *(const half8*)&projp[((nt * 3 + kb) * 4 + l4) * 128 + l15 * 8];
                acc = MFMA_F16(oa[kb], bw, acc, 0, 0, 0);
            }
            int n = nt * 16 + l15;
            float pb = proj_b[n];
            #pragma unroll
            for (int r = 0; r < 4; ++r)
                x2v[nt][r] = tvalid[r] ? (x[tbase[r] + n] + acc[r] + pb) : 0.f;
        }
    }

    // ---- LN2 in-register: per-token reduce over l15 (16 lanes) + nt ----
    float mu2[4], rs2[4];
    #pragma unroll
    for (int r = 0; r < 4; ++r) {
        float sum = 0.f, sq = 0.f;
        #pragma unroll
        for (int nt = 0; nt < 6; ++nt) { float v = x2v[nt][r]; sum += v; sq += v * v; }
        sum += __shfl_xor(sum, 1); sq += __shfl_xor(sq, 1);
        sum += __shfl_xor(sum, 2); sq += __shfl_xor(sq, 2);
        sum += __shfl_xor(sum, 4); sq += __shfl_xor(sq, 4);
        sum += __shfl_xor(sum, 8); sq += __shfl_xor(sq, 8);
        float mm = sum * (1.0f / 96.0f);
        mu2[r] = mm;
        rs2[r] = rsqrtf(sq * (1.0f / 96.0f) - mm * mm + 1e-5f);
    }

    // ---- x~ -> XT A-tiles (own rows; overwrites Ou after oa read) ----
    #pragma unroll
    for (int nt = 0; nt < 6; ++nt) {
        int n = nt * 16 + l15;
        float gg = g2[n], bbv = bb2[n];
        #pragma unroll
        for (int r = 0; r < 4; ++r) {
            int tok = wv * 16 + l4 * 4 + r;
            XT[(n >> 3) * 512 + tok * 8 + (n & 7)] =
                (_Float16)((x2v[nt][r] - mu2[r]) * rs2[r] * gg + bbv);
        }
    }

    // ---- MLP GEMM1 + GELU -> YT tiles (own rows) ----
    {
        half8 a[3];
        #pragma unroll
        for (int kb = 0; kb < 3; ++kb)
            a[kb] = *(half8*)&XT[(kb * 4 + l4) * 512 + (wv * 16 + l15) * 8];
        for (int nt = 0; nt < 6; ++nt) {
            f32x4 acc = {0.f, 0.f, 0.f, 0.f};
            #pragma unroll
            for (int kb = 0; kb < 3; ++kb) {
                half8 bw = *(const half8*)&w1p[((nt * 3 + kb) * 4 + l4) * 128 + l15 * 8];
                acc = MFMA_F16(a[kb], bw, acc, 0, 0, 0);
            }
            int n = nt * 16 + l15;
            float bias = bi1[n];
            #pragma unroll
            for (int r = 0; r < 4; ++r) {
                int tok = wv * 16 + l4 * 4 + r;
                float v = acc[r] + bias;
                v = 0.5f * v * (1.0f + erff(v * 0.70710678118654752f));
                YT[(n >> 3) * 512 + tok * 8 + (n & 7)] = (_Float16)v;
            }
        }
    }

    // ---- MLP GEMM2 + final residual -> out ----
    {
        half8 a[3];
        #pragma unroll
        for (int kb = 0; kb < 3; ++kb)
            a[kb] = *(half8*)&YT[(kb * 4 + l4) * 512 + (wv * 16 + l15) * 8];
        for (int nt = 0; nt < 6; ++nt) {
            f32x4 acc = {0.f, 0.f, 0.f, 0.f};
            #pragma unroll
            for (int kb = 0; kb < 3; ++kb) {
                half8 bw = *(const half8*)&w2p[((nt * 3 + kb) * 4 + l4) * 128 + l15 * 8];
                acc = MFMA_F16(a[kb], bw, acc, 0, 0, 0);
            }
            int n = nt * 16 + l15;
            float bias = bi2[n];
            #pragma unroll
            for (int r = 0; r < 4; ++r) {
                if (tvalid[r])
                    out[tbase[r] + n] = x2v[nt][r] + acc[r] + bias;
            }
        }
    }
}

extern "C" void kernel_launch(void* const* d_in, const int* in_sizes, int n_in,
                              void* d_out, int out_size, void* d_ws, size_t ws_size,
                              hipStream_t stream) {
    (void)in_sizes; (void)n_in; (void)ws_size; (void)out_size;
    const float* x         = (const float*)d_in[0];
    const float* qkv_w     = (const float*)d_in[1];
    const float* qkv_b     = (const float*)d_in[2];
    const float* attn_bias = (const float*)d_in[3];
    const float* proj_w    = (const float*)d_in[4];
    const float* proj_b    = (const float*)d_in[5];
    const float* ln1_g     = (const float*)d_in[6];
    const float* ln1_b     = (const float*)d_in[7];
    const float* ln2_g     = (const float*)d_in[8];
    const float* ln2_b     = (const float*)d_in[9];
    const float* mlp_w1    = (const float*)d_in[10];
    const float* mlp_b1    = (const float*)d_in[11];
    const float* mlp_w2    = (const float*)d_in[12];
    const float* mlp_b2    = (const float*)d_in[13];
    float* out = (float*)d_out;
    _Float16* wpack = (_Float16*)d_ws;

    pack_w6<<<216, 256, 0, stream>>>(qkv_w, proj_w, mlp_w1, mlp_w2, wpack);
    attn_k6<<<64 * 64, 256, 0, stream>>>(x, qkv_b, attn_bias, proj_b,
                                         ln1_g, ln1_b, ln2_g, ln2_b,
                                         mlp_b1, mlp_b2, wpack, out);
}

// Round 10
// 131.343 us; speedup vs baseline: 7.4696x; 1.2198x over previous
//
#include <hip/hip_runtime.h>
#include <math.h>

typedef _Float16 half8 __attribute__((ext_vector_type(8)));
typedef float f32x4 __attribute__((ext_vector_type(4)));

#define MFMA_F16 __builtin_amdgcn_mfma_f32_16x16x32_f16

constexpr int WS = 7, HH = 56, HW = 3136;

// d_ws layout (fp16 element offsets)
constexpr int QKVP_OFF  = 0;       // 27648
constexpr int PROJP_OFF = 27648;   // 9216
constexpr int W1P_OFF   = 36864;   // 9216
constexpr int W2P_OFF   = 46080;   // 9216

__device__ __forceinline__ int lab7(int v) { return v < 49 ? 0 : (v < 53 ? 1 : 2); }
__device__ __forceinline__ int div7g(int v) { return (v * 9363) >> 16; }  // valid 0..63

// ---------------------------------------------------------------------------
// Weight pre-pack: f32 [K][N] row-major -> fp16 B-fragment tiles
// ---------------------------------------------------------------------------
__global__ __launch_bounds__(256) void pack_w7(
    const float* __restrict__ qkv_w, const float* __restrict__ proj_w,
    const float* __restrict__ w1, const float* __restrict__ w2,
    _Float16* __restrict__ ws)
{
    int i = blockIdx.x * 256 + threadIdx.x;
    const float* src; int ncol, local;
    if (i < 27648)      { src = qkv_w;  ncol = 288; local = i; }
    else if (i < 36864) { src = proj_w; ncol = 96;  local = i - 27648; }
    else if (i < 46080) { src = w1;     ncol = 96;  local = i - 36864; }
    else                { src = w2;     ncol = 96;  local = i - 46080; }
    int j = local & 7, col = (local >> 3) & 15, ksub = (local >> 7) & 3;
    int rest = local >> 9;
    int kb = rest % 3, nt = rest / 3;
    int k = kb * 32 + ksub * 8 + j, n = nt * 16 + col;
    ws[i] = (_Float16)src[k * ncol + n];
}

// ---------------------------------------------------------------------------
// Fully fused Swin block (one block per batch-window, 3 barriers, 4 blk/CU).
// LDS planes (12 KB each region), aliased over time:
//   planes 0-11 : XLN -> Qu -> Pu(lo) -> Ou -> XT
//   planes 12-23: Ku -> Pu(hi) -> YT
//   planes 24-35: Vu
// ---------------------------------------------------------------------------
__global__ __launch_bounds__(256, 4) void attn_k7(
    const float* __restrict__ x,
    const float* __restrict__ qkv_b,
    const float* __restrict__ attn_bias,
    const float* __restrict__ proj_b,
    const float* __restrict__ ln1_g,
    const float* __restrict__ ln1_b,
    const float* __restrict__ ln2_g,
    const float* __restrict__ ln2_b,
    const float* __restrict__ mlp_b1,
    const float* __restrict__ mlp_b2,
    const _Float16* __restrict__ wpack,
    float* __restrict__ out)
{
    __shared__ __align__(16) char smem[36864];
    __shared__ float g1[96], b1[96], g2[96], bb2[96], bi1[96], bi2[96];

    _Float16*  XLN = (_Float16*)smem;
    _Float16*  Qu  = (_Float16*)smem;
    _Float16*  Ku  = (_Float16*)(smem + 12288);
    _Float16*  Vu  = (_Float16*)(smem + 24576);
    _Float16*  Pu  = (_Float16*)smem;            // 24 planes spanning Qu+Ku
    _Float16*  Ou  = (_Float16*)smem;            // planes 0..11, own rows
    _Float16*  XT  = (_Float16*)smem;            // MLP x~ tiles, planes 0..11
    _Float16*  YT  = (_Float16*)(smem + 12288);  // MLP mid tiles, planes 12..23

    const _Float16* qkvp  = wpack + QKVP_OFF;
    const _Float16* projp = wpack + PROJP_OFF;
    const _Float16* w1p   = wpack + W1P_OFF;
    const _Float16* w2p   = wpack + W2P_OFF;

    const int blk = blockIdx.x;
    const int b   = blk >> 6;
    const int w   = blk & 63;
    const int wh  = w >> 3, ww = w & 7;
    const int tid = threadIdx.x;
    const int wv  = tid >> 6, lane = tid & 63;
    const int l15 = lane & 15, l4 = lane >> 4;

    if (tid < 96) {
        g1[tid] = ln1_g[tid]; b1[tid] = ln1_b[tid];
        g2[tid] = ln2_g[tid]; bb2[tid] = ln2_b[tid];
        bi1[tid] = mlp_b1[tid]; bi2[tid] = mlp_b2[tid];
    }

    // ---- zero V pad region ----
    for (int idx = tid; idx < 768; idx += 256)
        ((uint4*)Vu)[idx] = make_uint4(0, 0, 0, 0);

    // ---- gather window (rolled) into registers: 4 threads/token x 24 ch ----
    const int t_own = tid >> 2, part = tid & 3;
    const bool active = (tid < 196);
    float4 xq[6];
    float m = 0.f, rinv = 0.f;
    if (active) {
        int i = div7g(t_own), j = t_own - i * 7;
        int row = wh * WS + i + 3; if (row >= HH) row -= HH;
        int col = ww * WS + j + 3; if (col >= HH) col -= HH;
        const float* xp = &x[(((size_t)b * HW + row * HH + col) * 96) + part * 24];
        #pragma unroll
        for (int q = 0; q < 6; ++q) xq[q] = *(const float4*)&xp[q * 4];
        float sum = 0.f, sq = 0.f;
        #pragma unroll
        for (int q = 0; q < 6; ++q) {
            sum += xq[q].x + xq[q].y + xq[q].z + xq[q].w;
            sq  += xq[q].x * xq[q].x + xq[q].y * xq[q].y
                 + xq[q].z * xq[q].z + xq[q].w * xq[q].w;
        }
        sum += __shfl_xor(sum, 1); sq += __shfl_xor(sq, 1);
        sum += __shfl_xor(sum, 2); sq += __shfl_xor(sq, 2);
        m = sum * (1.0f / 96.0f);
        rinv = rsqrtf(sq * (1.0f / 96.0f) - m * m + 1e-5f);
    }
    __syncthreads();   // B1: consts ready; V zeroed

    // ---- normalize -> XLN A-tiles (own-wave rows: thread 4t is in wave t>>4)
    if (active) {
        #pragma unroll
        for (int cc = 0; cc < 3; ++cc) {
            half8 pk;
            #pragma unroll
            for (int j = 0; j < 8; ++j) {
                int c = part * 24 + cc * 8 + j;
                float v; int qi = cc * 2 + (j >> 2);
                if ((j & 3) == 0) v = xq[qi].x;
                else if ((j & 3) == 1) v = xq[qi].y;
                else if ((j & 3) == 2) v = xq[qi].z;
                else v = xq[qi].w;
                pk[j] = (_Float16)((v - m) * rinv * g1[c] + b1[c]);
            }
            *(half8*)&XLN[(part * 3 + cc) * 512 + t_own * 8] = pk;
        }
    }
    // NO barrier: QKV A-frags read own-stripe rows written by this wave.

    // ---- QKV GEMM: wave wv owns token tile mt=wv; 3 uniform store loops ----
    {
        half8 a[3];
        #pragma unroll
        for (int kb = 0; kb < 3; ++kb)
            a[kb] = *(half8*)&XLN[(kb * 4 + l4) * 512 + (wv * 16 + l15) * 8];
        const int tok0 = wv * 16 + l4 * 4;

        // Q: nt 0..5 (unguarded rows: garbage q>=49 replaced in softmax)
        #pragma unroll
        for (int nt = 0; nt < 6; ++nt) {
            f32x4 acc = {0.f, 0.f, 0.f, 0.f};
            #pragma unroll
            for (int kb = 0; kb < 3; ++kb) {
                half8 bw = *(const half8*)&qkvp[((nt * 3 + kb) * 4 + l4) * 128 + l15 * 8];
                acc = MFMA_F16(a[kb], bw, acc, 0, 0, 0);
            }
            int n = nt * 16 + l15;
            float bias = qkv_b[n];
            int h = n >> 5, d = n & 31;
            _Float16* qp = &Qu[(h * 4 + (d >> 3)) * 512 + tok0 * 8 + (d & 7)];
            #pragma unroll
            for (int r = 0; r < 4; ++r)
                qp[r * 8] = (_Float16)(acc[r] + bias);
        }
        // K: nt 6..11 (unguarded)
        #pragma unroll
        for (int nt = 6; nt < 12; ++nt) {
            f32x4 acc = {0.f, 0.f, 0.f, 0.f};
            #pragma unroll
            for (int kb = 0; kb < 3; ++kb) {
                half8 bw = *(const half8*)&qkvp[((nt * 3 + kb) * 4 + l4) * 128 + l15 * 8];
                acc = MFMA_F16(a[kb], bw, acc, 0, 0, 0);
            }
            int n = nt * 16 + l15;
            float bias = qkv_b[n];
            int n2 = n - 96, h = n2 >> 5, d = n2 & 31;
            _Float16* kp = &Ku[(h * 4 + (d >> 3)) * 512 + tok0 * 8 + (d & 7)];
            #pragma unroll
            for (int r = 0; r < 4; ++r)
                kp[r * 8] = (_Float16)(acc[r] + bias);
        }
        // V: nt 12..17 (guarded: pad rows must stay zero)
        #pragma unroll
        for (int nt = 12; nt < 18; ++nt) {
            f32x4 acc = {0.f, 0.f, 0.f, 0.f};
            #pragma unroll
            for (int kb = 0; kb < 3; ++kb) {
                half8 bw = *(const half8*)&qkvp[((nt * 3 + kb) * 4 + l4) * 128 + l15 * 8];
                acc = MFMA_F16(a[kb], bw, acc, 0, 0, 0);
            }
            int n = nt * 16 + l15;
            float bias = qkv_b[n];
            int n2 = n - 192, h = n2 >> 5, d = n2 & 31;
            #pragma unroll
            for (int r = 0; r < 4; ++r) {
                int tok = tok0 + r;
                if (tok < 49)
                    Vu[(h * 8 + (tok >> 3)) * 256 + d * 8 + (tok & 7)] = (_Float16)(acc[r] + bias);
            }
        }
    }
    __syncthreads();   // B2: K/V cross-wave reads below

    // ---- scores: wave wv owns q-tile; all heads, K=32 single MFMA ----
    f32x4 s[3][4];
    #pragma unroll
    for (int h = 0; h < 3; ++h) {
        half8 qf = *(half8*)&Qu[(h * 4 + l4) * 512 + (wv * 16 + l15) * 8];
        #pragma unroll
        for (int nt = 0; nt < 4; ++nt) {
            half8 kf = *(half8*)&Ku[(h * 4 + l4) * 512 + (nt * 16 + l15) * 8];
            f32x4 z = {0.f, 0.f, 0.f, 0.f};
            s[h][nt] = MFMA_F16(qf, kf, z, 0, 0, 0);
        }
    }
    __syncthreads();   // B3: Q,K dead for ALL waves -> P may overwrite

    // ---- softmax, NO max-subtraction (scores bounded |v|<~8) ----
    {
        const float scale = 0.17677669529663687f;
        int qq[4]; bool qo[4];
        int kc[4];            // clamped k for bias address
        bool keep[4][4];      // (r, nt) mask, head-independent
        #pragma unroll
        for (int nt = 0; nt < 4; ++nt) {
            int k = nt * 16 + l15;
            kc[nt] = k < 49 ? k : 48;
        }
        #pragma unroll
        for (int r = 0; r < 4; ++r) {
            qq[r] = wv * 16 + l4 * 4 + r;
            qo[r] = qq[r] < 49;
            int qcl = qo[r] ? qq[r] : 48;
            int qi = div7g(qcl), qj = qcl - qi * 7;
            int lqr = lab7(wh * WS + qi), lqc = lab7(ww * WS + qj);
            #pragma unroll
            for (int nt = 0; nt < 4; ++nt) {
                int k = nt * 16 + l15;
                int ki = div7g(kc[nt]), kj = kc[nt] - ki * 7;
                keep[r][nt] = qo[r] && (k < 49) &&
                              (lqr == lab7(wh * WS + ki)) &&
                              (lqc == lab7(ww * WS + kj));
            }
        }
        #pragma unroll
        for (int h = 0; h < 3; ++h) {
            #pragma unroll
            for (int r = 0; r < 4; ++r) {
                int qcl = qo[r] ? qq[r] : 48;
                const float* bp = attn_bias + (h * 49 + qcl) * 49;
                float e[4], sum = 0.f;
                #pragma unroll
                for (int nt = 0; nt < 4; ++nt) {
                    float v = fmaf(s[h][nt][r], scale, bp[kc[nt]]);
                    e[nt] = keep[r][nt] ? __expf(v) : 0.f;
                    sum += e[nt];
                }
                sum += __shfl_xor(sum, 1);
                sum += __shfl_xor(sum, 2);
                sum += __shfl_xor(sum, 4);
                sum += __shfl_xor(sum, 8);
                float inv = qo[r] ? __builtin_amdgcn_rcpf(sum) : 0.f;
                #pragma unroll
                for (int nt = 0; nt < 4; ++nt) {
                    int k = nt * 16 + l15;
                    Pu[(h * 8 + (k >> 3)) * 512 + qq[r] * 8 + (k & 7)] =
                        (_Float16)(e[nt] * inv);
                }
            }
        }
    }
    // Everything below: wave-private own-stripe rows or read-only V.

    // ---- PV: O = P @ V (own q-stripe); O over own P rows ----
    #pragma unroll
    for (int h = 0; h < 3; ++h) {
        half8 pa0 = *(half8*)&Pu[(h * 8 + 0 + l4) * 512 + (wv * 16 + l15) * 8];
        half8 pa1 = *(half8*)&Pu[(h * 8 + 4 + l4) * 512 + (wv * 16 + l15) * 8];
        #pragma unroll
        for (int ntd = 0; ntd < 2; ++ntd) {
            f32x4 acc = {0.f, 0.f, 0.f, 0.f};
            half8 vb0 = *(half8*)&Vu[(h * 8 + 0 + l4) * 256 + (ntd * 16 + l15) * 8];
            acc = MFMA_F16(pa0, vb0, acc, 0, 0, 0);
            half8 vb1 = *(half8*)&Vu[(h * 8 + 4 + l4) * 256 + (ntd * 16 + l15) * 8];
            acc = MFMA_F16(pa1, vb1, acc, 0, 0, 0);
            int c = h * 32 + ntd * 16 + l15;
            #pragma unroll
            for (int r = 0; r < 4; ++r) {
                int tok = wv * 16 + l4 * 4 + r;
                Ou[(c >> 3) * 512 + tok * 8 + (c & 7)] = (_Float16)acc[r];
            }
        }
    }

    // ---- proj + residual into REGISTERS (x2 = x + attn_out) ----
    float x2v[6][4];
    size_t tbase[4]; bool tvalid[4];
    {
        half8 oa[3];
        #pragma unroll
        for (int kb = 0; kb < 3; ++kb)
            oa[kb] = *(half8*)&Ou[(kb * 4 + l4) * 512 + (wv * 16 + l15) * 8];

        #pragma unroll
        for (int r = 0; r < 4; ++r) {
            int tok = wv * 16 + l4 * 4 + r;
            tvalid[r] = (tok < 49);
            int i = div7g(tok & 63), j = (tok & 63) - i * 7;
            int row = wh * WS + i + 3; if (row >= HH) row -= HH;
            int col = ww * WS + j + 3; if (col >= HH) col -= HH;
            tbase[r] = ((size_t)b * HW + row * HH + col) * 96;
        }
        for (int nt = 0; nt < 6; ++nt) {
            f32x4 acc = {0.f, 0.f, 0.f, 0.f};
            #pragma unroll
            for (int kb = 0; kb < 3; ++kb) {
                half8 bw = *(const half8*)&projp[((nt * 3 + kb) * 4 + l4) * 128 + l15 * 8];
                acc = MFMA_F16(oa[kb], bw, acc, 0, 0, 0);
            }
            int n = nt * 16 + l15;
            float pb = proj_b[n];
            #pragma unroll
            for (int r = 0; r < 4; ++r)
                x2v[nt][r] = tvalid[r] ? (x[tbase[r] + n] + acc[r] + pb) : 0.f;
        }
    }

    // ---- LN2 in-register: per-token reduce over l15 (16 lanes) + nt ----
    float mu2[4], rs2[4];
    #pragma unroll
    for (int r = 0; r < 4; ++r) {
        float sum = 0.f, sq = 0.f;
        #pragma unroll
        for (int nt = 0; nt < 6; ++nt) { float v = x2v[nt][r]; sum += v; sq += v * v; }
        sum += __shfl_xor(sum, 1); sq += __shfl_xor(sq, 1);
        sum += __shfl_xor(sum, 2); sq += __shfl_xor(sq, 2);
        sum += __shfl_xor(sum, 4); sq += __shfl_xor(sq, 4);
        sum += __shfl_xor(sum, 8); sq += __shfl_xor(sq, 8);
        float mm = sum * (1.0f / 96.0f);
        mu2[r] = mm;
        rs2[r] = rsqrtf(sq * (1.0f / 96.0f) - mm * mm + 1e-5f);
    }

    // ---- x~ -> XT A-tiles (own rows; overwrites Ou after oa read) ----
    #pragma unroll
    for (int nt = 0; nt < 6; ++nt) {
        int n = nt * 16 + l15;
        float gg = g2[n], bbv = bb2[n];
        #pragma unroll
        for (int r = 0; r < 4; ++r) {
            int tok = wv * 16 + l4 * 4 + r;
            XT[(n >> 3) * 512 + tok * 8 + (n & 7)] =
                (_Float16)((x2v[nt][r] - mu2[r]) * rs2[r] * gg + bbv);
        }
    }

    // ---- MLP GEMM1 + GELU (tanh-form via sigmoid) -> YT tiles (own rows) ----
    {
        half8 a[3];
        #pragma unroll
        for (int kb = 0; kb < 3; ++kb)
            a[kb] = *(half8*)&XT[(kb * 4 + l4) * 512 + (wv * 16 + l15) * 8];
        for (int nt = 0; nt < 6; ++nt) {
            f32x4 acc = {0.f, 0.f, 0.f, 0.f};
            #pragma unroll
            for (int kb = 0; kb < 3; ++kb) {
                half8 bw = *(const half8*)&w1p[((nt * 3 + kb) * 4 + l4) * 128 + l15 * 8];
                acc = MFMA_F16(a[kb], bw, acc, 0, 0, 0);
            }
            int n = nt * 16 + l15;
            float bias = bi1[n];
            #pragma unroll
            for (int r = 0; r < 4; ++r) {
                int tok = wv * 16 + l4 * 4 + r;
                float v = acc[r] + bias;
                // gelu(v) ~= v * sigmoid(v*(1.5957691 + 0.0713548*v^2))
                float v2 = v * v;
                float c2 = fmaf(v2, 0.0713548163f, 1.5957691216f);
                float z  = v * c2;
                float ex = __expf(-z);
                float y  = v * __builtin_amdgcn_rcpf(1.0f + ex);
                YT[(n >> 3) * 512 + tok * 8 + (n & 7)] = (_Float16)y;
            }
        }
    }

    // ---- MLP GEMM2 + final residual -> out ----
    {
        half8 a[3];
        #pragma unroll
        for (int kb = 0; kb < 3; ++kb)
            a[kb] = *(half8*)&YT[(kb * 4 + l4) * 512 + (wv * 16 + l15) * 8];
        for (int nt = 0; nt < 6; ++nt) {
            f32x4 acc = {0.f, 0.f, 0.f, 0.f};
            #pragma unroll
            for (int kb = 0; kb < 3; ++kb) {
                half8 bw = *(const half8*)&w2p[((nt * 3 + kb) * 4 + l4) * 128 + l15 * 8];
                acc = MFMA_F16(a[kb], bw, acc, 0, 0, 0);
            }
            int n = nt * 16 + l15;
            float bias = bi2[n];
            #pragma unroll
            for (int r = 0; r < 4; ++r) {
                if (tvalid[r])
                    out[tbase[r] + n] = x2v[nt][r] + acc[r] + bias;
            }
        }
    }
}

extern "C" void kernel_launch(void* const* d_in, const int* in_sizes, int n_in,
                              void* d_out, int out_size, void* d_ws, size_t ws_size,
                              hipStream_t stream) {
    (void)in_sizes; (void)n_in; (void)ws_size; (void)out_size;
    const float* x         = (const float*)d_in[0];
    const float* qkv_w     = (const float*)d_in[1];
    const float* qkv_b     = (const float*)d_in[2];
    const float* attn_bias = (const float*)d_in[3];
    const float* proj_w    = (const float*)d_in[4];
    const float* proj_b    = (const float*)d_in[5];
    const float* ln1_g     = (const float*)d_in[6];
    const float* ln1_b     = (const float*)d_in[7];
    const float* ln2_g     = (const float*)d_in[8];
    const float* ln2_b     = (const float*)d_in[9];
    const float* mlp_w1    = (const float*)d_in[10];
    const float* mlp_b1    = (const float*)d_in[11];
    const float* mlp_w2    = (const float*)d_in[12];
    const float* mlp_b2    = (const float*)d_in[13];
    float* out = (float*)d_out;
    _Float16* wpack = (_Float16*)d_ws;

    pack_w7<<<216, 256, 0, stream>>>(qkv_w, proj_w, mlp_w1, mlp_w2, wpack);
    attn_k7<<<64 * 64, 256, 0, stream>>>(x, qkv_b, attn_bias, proj_b,
                                         ln1_g, ln1_b, ln2_g, ln2_b,
                                         mlp_b1, mlp_b2, wpack, out);
}